// Round 4
// baseline (623.602 us; speedup 1.0000x reference)
//
#include <hip/hip_runtime.h>

// EDTAttention MI355X, round 6: revert round-5 fusion (write-amplification
// regression: 314MB out writes, partial 128B lines across >L2 working set).
// Back to round-2 structure (606us known-good). New: kA2V dumps Y directly
// in VV-permuted LDS layout (kills 64 scalar ds_read_u16/thread gather);
// kB pass-2 MFMA cluster wrapped in s_setprio (barrier-free per-wave phase,
// attn-like regime where T5 measured +4-7%).
//
// Index algebra (verified in earlier rounds):
//   Y[b,t,j] = xf @ qkv_w.T + qkv_b,  t = s*256+n, j in [0,256)
//   Q[b,h,s,d]  = Y[b, s*256 +       h*8+ns, j]   d = ns*256+j
//   K[b,h,s,d]  = Y[b, s*256 +  64 + h*8+ns, j]
//   VH[b,h,s,d] = Y[b, s*256 + 128 + h*8+ns, j]
//   VV[b,h,t,d] = Y[b, (h*32+d/64)*256 + 192 + (t/32)*8 + (t%32)/4, (t%4)*64 + d%64]
//   kA2V inverse: element (m=n-192, j) -> dm=j&63, t=32*(m>>3)+4*(m&7)+(j>>6)

using half_t = _Float16;
using half8 = __attribute__((ext_vector_type(8))) _Float16;
using f32x4 = __attribute__((ext_vector_type(4))) float;

#define NTOK 524288      // 8*256*256

// async global->LDS, 16B per lane, LDS dest = wave-uniform base + lane*16
#define GLDS(g, l) __builtin_amdgcn_global_load_lds( \
    (const __attribute__((address_space(1))) void*)(g), \
    (__attribute__((address_space(3))) void*)(l), 16, 0, 0)

// ---- workspace layout (bytes) ----
#define WS_Q      0
#define WS_K      67108864
#define WS_VH     134217728
#define WS_VV     201326592
#define WS_XHV    268435456
#define WS_NQ     335544320
#define WS_NK     335609856
#define WS_WH     335675392
#define WS_WP     335708160

// ---------------- weight prep: fp32 -> f16 ----------------
__global__ void kW0(const float* __restrict__ qkv_w, const float* __restrict__ proj_w,
                    half_t* __restrict__ Wh, half_t* __restrict__ Wp) {
    int tid = threadIdx.x;
    for (int i = tid; i < 256 * 64; i += 256) Wh[i] = (half_t)qkv_w[i];
    for (int i = tid; i < 64 * 64; i += 256) Wp[i] = (half_t)proj_w[i];
}

// ---------------- Y-tile MFMA core: acc[mt][i] over 64 tokens x 256 j, K=64 ----
__device__ inline void y_tile_mfma(const float* __restrict__ xb,
                                   const half_t* __restrict__ Wh,
                                   int tbase, int hi, int lo,
                                   f32x4 (&acc)[4][4], int wave, int lane) {
    const int l15 = lane & 15, quad = lane >> 4;
#pragma unroll
    for (int kc = 0; kc < 2; ++kc) {
        const int c = kc * 32 + quad * 8;
        half8 afr[4];
#pragma unroll
        for (int mt = 0; mt < 4; ++mt) {
            int m = mt * 16 + l15;
            int token = tbase + (m >> 3) * hi + (m & 7) * lo;
            const float* p = xb + (size_t)token * 64 + c;
            f32x4 f0 = *(const f32x4*)p;
            f32x4 f1 = *(const f32x4*)(p + 4);
            half8 a;
            a[0] = (half_t)f0[0]; a[1] = (half_t)f0[1]; a[2] = (half_t)f0[2]; a[3] = (half_t)f0[3];
            a[4] = (half_t)f1[0]; a[5] = (half_t)f1[1]; a[6] = (half_t)f1[2]; a[7] = (half_t)f1[3];
            afr[mt] = a;
        }
#pragma unroll
        for (int i = 0; i < 4; ++i) {
            int j = (wave * 4 + i) * 16 + l15;
            half8 bfr = *(const half8*)(Wh + j * 64 + c);
#pragma unroll
            for (int mt = 0; mt < 4; ++mt)
                acc[mt][i] = __builtin_amdgcn_mfma_f32_16x16x32_f16(afr[mt], bfr, acc[mt][i], 0, 0, 0);
        }
    }
}

// row-major dump: ylds[m][j], stride 264
__device__ inline void y_dump_rowmajor(f32x4 (&acc)[4][4], const float* __restrict__ qkv_b,
                                       half_t* ylds, int wave, int lane) {
    const int l15 = lane & 15, quad = lane >> 4;
#pragma unroll
    for (int i = 0; i < 4; ++i) {
        int j = (wave * 4 + i) * 16 + l15;
        float bj = qkv_b[j];
#pragma unroll
        for (int mt = 0; mt < 4; ++mt)
#pragma unroll
            for (int r = 0; r < 4; ++r)
                ylds[(mt * 16 + quad * 4 + r) * 264 + j] = (half_t)(acc[mt][i][r] + bj);
    }
}

// transposed dump: yldsT[j][m], stride 72
__device__ inline void y_dump_transposed(f32x4 (&acc)[4][4], const float* __restrict__ qkv_b,
                                         half_t* yldsT, int wave, int lane) {
    const int l15 = lane & 15, quad = lane >> 4;
#pragma unroll
    for (int i = 0; i < 4; ++i) {
        int j = (wave * 4 + i) * 16 + l15;
        float bj = qkv_b[j];
#pragma unroll
        for (int mt = 0; mt < 4; ++mt)
#pragma unroll
            for (int r = 0; r < 4; ++r)
                yldsT[j * 72 + mt * 16 + quad * 4 + r] = (half_t)(acc[mt][i][r] + bj);
    }
}

// ---------------- A1: Q and K (g=0,1) + norms ----------------
__global__ __launch_bounds__(256) void kA1(const float* __restrict__ x,
                                           const half_t* __restrict__ Wh,
                                           const float* __restrict__ qkv_b,
                                           half_t* __restrict__ Q, half_t* __restrict__ K,
                                           float* __restrict__ normQ, float* __restrict__ normK) {
    __shared__ half_t ylds[64 * 264];
    __shared__ float scr[256];
    int idx = blockIdx.x;
    int sb = idx & 31; idx >>= 5;
    int h = idx & 7; idx >>= 3;
    int g = idx & 1; int b = idx >> 1;
    int s0 = sb * 8;
    int n0 = g * 64 + h * 8;
    int tid = threadIdx.x, wave = tid >> 6, lane = tid & 63;
    const float* xb = x + (size_t)b * 65536 * 64;
    f32x4 acc[4][4];
#pragma unroll
    for (int a = 0; a < 4; ++a)
#pragma unroll
        for (int c = 0; c < 4; ++c) acc[a][c] = {0.f, 0.f, 0.f, 0.f};
    y_tile_mfma(xb, Wh, s0 * 256 + n0, 256, 1, acc, wave, lane);
    y_dump_rowmajor(acc, qkv_b, ylds, wave, lane);
    __syncthreads();
    half_t* dst = (g == 0 ? Q : K) + ((size_t)(b * 8 + h) * 256 + s0) * 2048;
    int ns = tid >> 5, jc = (tid & 31) * 8;
#pragma unroll
    for (int si = 0; si < 8; ++si) {
        half8 v = *(const half8*)&ylds[(si * 8 + ns) * 264 + jc];
        *(half8*)(dst + (size_t)si * 2048 + ns * 256 + jc) = v;
    }
    float sum = 0.f;
#pragma unroll
    for (int nn = 0; nn < 8; ++nn) {
        half8 v = *(const half8*)&ylds[((tid >> 5) * 8 + nn) * 264 + (tid & 31) * 8];
#pragma unroll
        for (int e = 0; e < 8; ++e) { float f = (float)v[e]; sum += f * f; }
    }
    scr[tid] = sum;
    __syncthreads();
    if (tid < 8) {
        float s = 0.f;
        for (int k2 = 0; k2 < 32; ++k2) s += scr[tid * 32 + k2];
        float* nd = (g == 0 ? normQ : normK);
        nd[(b * 8 + h) * 256 + s0 + tid] = s;
    }
}

// ---------------- A2H: V_H (g=2) -> VH[bh][d][t], wide stores ----------------
__global__ __launch_bounds__(256) void kA2H(const float* __restrict__ x,
                                            const half_t* __restrict__ Wh,
                                            const float* __restrict__ qkv_b,
                                            half_t* __restrict__ VH) {
    __shared__ half_t yldsT[256 * 72];
    int idx = blockIdx.x;
    int sb = idx & 3; idx >>= 2;
    int nn = idx & 63; int b = idx >> 6;
    int h = nn >> 3, ns = nn & 7;
    int n = 128 + nn;
    int s0 = sb * 64;
    int tid = threadIdx.x, wave = tid >> 6, lane = tid & 63;
    const float* xb = x + (size_t)b * 65536 * 64;
    f32x4 acc[4][4];
#pragma unroll
    for (int a = 0; a < 4; ++a)
#pragma unroll
        for (int c = 0; c < 4; ++c) acc[a][c] = {0.f, 0.f, 0.f, 0.f};
    y_tile_mfma(xb, Wh, s0 * 256 + n, 2048, 256, acc, wave, lane);  // m == local s
    y_dump_transposed(acc, qkv_b, yldsT, wave, lane);
    __syncthreads();
    int jl = lane >> 3, tc = lane & 7;
    half_t* base = VH + ((size_t)(b * 8 + h) * 2048 + ns * 256) * 256 + s0 + tc * 8;
#pragma unroll
    for (int u = 0; u < 8; ++u) {
        int j = wave * 64 + u * 8 + jl;
        half8 v = *(const half8*)&yldsT[j * 72 + tc * 8];
        *(half8*)(base + (size_t)j * 256) = v;
    }
}

// ---------------- A2V: V_V (g=3) -> VV[bh][d][t], direct-permuted dump -------
// Y element (m = n-192, j) lands at VV slot dm = j&63, t = 32*(m>>3)+4*(m&7)
// + (j>>6) (inverse of the reference permutation; algebra matches the old
// gather: t = w*64+tc*8+e <-> m = w*16+(tc>>2)*8+(tc&3)*2+(e>>2), j=(e&3)*64+dm).
// Removes 64 scalar ds_read_u16 per thread; stores are 2x512B contiguous
// segments per wave instruction.
__global__ __launch_bounds__(256) void kA2V(const float* __restrict__ x,
                                            const half_t* __restrict__ Wh,
                                            const float* __restrict__ qkv_b,
                                            half_t* __restrict__ VV) {
    __shared__ half_t vlds[64 * 264];            // [dm][t], row stride 264
    int idx = blockIdx.x;
    int st = idx & 255; int b = idx >> 8;
    int h = st >> 5;
    int tid = threadIdx.x, wave = tid >> 6, lane = tid & 63;
    const float* xb = x + (size_t)b * 65536 * 64;
    f32x4 acc[4][4];
#pragma unroll
    for (int a = 0; a < 4; ++a)
#pragma unroll
        for (int c = 0; c < 4; ++c) acc[a][c] = {0.f, 0.f, 0.f, 0.f};
    y_tile_mfma(xb, Wh, st * 256 + 192, 8, 1, acc, wave, lane);  // m == n-192
    {
        const int l15 = lane & 15, quad = lane >> 4;
#pragma unroll
        for (int i = 0; i < 4; ++i) {
            int j = (wave * 4 + i) * 16 + l15;
            float bj = qkv_b[j];
            int dm = j & 63;
            int jc = j >> 6;
#pragma unroll
            for (int mt = 0; mt < 4; ++mt)
#pragma unroll
                for (int r = 0; r < 4; ++r) {
                    int m = mt * 16 + quad * 4 + r;
                    int t = 32 * (m >> 3) + 4 * (m & 7) + jc;
                    vlds[dm * 264 + t] = (half_t)(acc[mt][i][r] + bj);
                }
        }
    }
    __syncthreads();
    half_t* base = VV + ((size_t)(b * 8 + h) * 2048 + (st & 31) * 64) * 256;
    int l31 = lane & 31, lh = lane >> 5;
#pragma unroll
    for (int u = 0; u < 8; ++u) {
        int dm = u * 8 + wave * 2 + lh;
        half8 v = *(const half8*)&vlds[dm * 264 + l31 * 8];
        *(half8*)(base + (size_t)dm * 256 + l31 * 8) = v;
    }
}

// ---------------- B: fused cosine attention, QBLK=64, 256 blocks x 1024 thr ----
// Pass 1 = LDS-staged double-buffered GEMM (round-4 structure, known 223us).
// Pass 2 MFMA cluster wrapped in s_setprio (barrier-free per-wave phase).
__global__ __launch_bounds__(1024, 4) void kB(const half_t* __restrict__ Q, const half_t* __restrict__ K,
                                              const half_t* __restrict__ VH, const half_t* __restrict__ VV,
                                              const float* __restrict__ normQ, const float* __restrict__ normK,
                                              const float* __restrict__ temp1, const float* __restrict__ temp2,
                                              half_t* __restrict__ xhv) {
    extern __shared__ char smem[];
    char* Ks0 = smem;                            // [256][64] halfs, 32768B
    char* Ks1 = smem + 32768;                    // 32768B
    char* Qs0 = smem + 65536;                    // [64][64] halfs, 8192B
    char* Qs1 = smem + 73728;                    // 8192B
    half_t* PH = (half_t*)(smem + 81920);        // [64][264]
    half_t* PV = (half_t*)(smem + 115712);       // [64][264] -> 149504
    float* redA = (float*)(smem + 149504);       // [1024]
    float* redB = (float*)(smem + 153600);       // [1024]
    float* mH  = (float*)(smem + 157696);        // [64]
    float* mV  = (float*)(smem + 157952);        // [64]
    float* rHs = (float*)(smem + 158208);        // [64]
    float* rVs = (float*)(smem + 158464);        // [64]
    float* rq  = (float*)(smem + 158720);        // [64]
    float* rk  = (float*)(smem + 158976);        // [256] -> end 160000

    int idx = blockIdx.x;
    int bh = idx & 63;              // XCD swizzle: same-bh sq-siblings share XCD
    int sqb = idx >> 6;             // 0..3
    int h = bh & 7, b = bh >> 3;
    int sq0 = sqb * 64;
    int tid = threadIdx.x, wave = tid >> 6, lane = tid & 63;
    int l15 = lane & 15, quad = lane >> 4;
    float t1 = temp1[h], t2 = temp2[h];
    const half_t* Qb = Q + (size_t)bh * 256 * 2048;
    const half_t* Kb = K + (size_t)bh * 256 * 2048;
    const half_t* VHb = VH + (size_t)bh * 2048 * 256;
    const half_t* VVb = VV + (size_t)bh * 2048 * 256;

    if (tid < 64) rq[tid] = 1.f / fmaxf(sqrtf(normQ[bh * 256 + sq0 + tid]), 1e-12f);
    if (tid < 256) rk[tid] = 1.f / fmaxf(sqrtf(normK[bh * 256 + tid]), 1e-12f);

    // ---- pass 1: sim = Q.K^T (64 x 256), LDS-staged. wave w owns t-tile w*16 ----
    {
        const int l7 = lane & 7, l8 = lane >> 3;
        // pre-swizzled global source: LDS slot (row r, s) holds global col16 s^(r&7).
        const int swzh = (l7 ^ (l8 & 7)) * 8;     // halfs offset within 64-half row
        const half_t* gK0 = Kb + (size_t)(wave * 8 + l8) * 2048 + swzh;         // rows [w*8, +8)
        const half_t* gK1 = Kb + (size_t)(128 + wave * 8 + l8) * 2048 + swzh;   // rows [128+w*8, +8)
        const half_t* gQ  = Qb + (size_t)(sq0 + (wave & 7) * 8 + l8) * 2048 + swzh;

        auto STAGE = [&](int kk, char* KsB, char* QsB) {
            const int off = kk * 64;              // BK=64 halfs per step
            GLDS(gK0 + off, KsB + wave * 1024);
            GLDS(gK1 + off, KsB + 16384 + wave * 1024);
            if (wave < 8) GLDS(gQ + off, QsB + wave * 1024);
        };

        f32x4 acc1[4];
#pragma unroll
        for (int a = 0; a < 4; ++a) acc1[a] = {0.f, 0.f, 0.f, 0.f};
        const int tcol = wave * 16 + l15;
        const int ts7 = tcol & 7;

        auto COMPUTE = [&](const char* KsB_, const char* QsB_) {
            const half_t* KsB = (const half_t*)KsB_;
            const half_t* QsB = (const half_t*)QsB_;
#pragma unroll
            for (int sub = 0; sub < 2; ++sub) {
                int c16 = sub * 4 + quad;         // 16B-slot index = d-slice
                half8 bfr = *(const half8*)(KsB + tcol * 64 + (c16 ^ ts7) * 8);
#pragma unroll
                for (int mt = 0; mt < 4; ++mt) {
                    int m = mt * 16 + l15;
                    half8 afr = *(const half8*)(QsB + m * 64 + (c16 ^ (m & 7)) * 8);
                    acc1[mt] = __builtin_amdgcn_mfma_f32_16x16x32_f16(afr, bfr, acc1[mt], 0, 0, 0);
                }
            }
        };

        STAGE(0, Ks0, Qs0);
        __syncthreads();                          // drains vmcnt -> buf0 ready (also rq/rk)
        for (int kk = 0; kk < 32; kk += 2) {
            if (kk + 1 < 32) STAGE(kk + 1, Ks1, Qs1);
            COMPUTE(Ks0, Qs0);
            __syncthreads();                      // buf1 staged + buf0 consumed
            if (kk + 2 < 32) STAGE(kk + 2, Ks0, Qs0);
            COMPUTE(Ks1, Qs1);
            __syncthreads();
        }
        float rkt = rk[tcol];
#pragma unroll
        for (int mt = 0; mt < 4; ++mt)
#pragma unroll
            for (int r = 0; r < 4; ++r) {
                int row = mt * 16 + quad * 4 + r;
                PH[row * 264 + tcol] = (half_t)(acc1[mt][r] * rq[row] * rkt);
            }
    }
    __syncthreads();

    // ---- dual softmax: thread owns (row r_, 16-col chunk c16) ----
    int r_ = tid & 63, cc = tid >> 6;
    half_t* phrow = &PH[r_ * 264 + cc * 16];
    half_t* pvrow = &PV[r_ * 264 + cc * 16];
    float mx = -3.4e38f, mn = 3.4e38f;
#pragma unroll
    for (int i2 = 0; i2 < 16; ++i2) { float v = (float)phrow[i2]; mx = fmaxf(mx, v); mn = fminf(mn, v); }
    redA[tid] = mx; redB[tid] = mn;
    __syncthreads();
    if (tid < 64) {
        float amx = -3.4e38f, amn = 3.4e38f;
#pragma unroll
        for (int q2 = 0; q2 < 16; ++q2) {
            amx = fmaxf(amx, redA[q2 * 64 + tid]);
            amn = fminf(amn, redB[q2 * 64 + tid]);
        }
        mH[tid] = (t1 >= 0.f) ? t1 * amx : t1 * amn;
        mV[tid] = (t2 >= 0.f) ? t2 * amx : t2 * amn;
    }
    __syncthreads();
    float mh = mH[r_], mv = mV[r_];
    float sh = 0.f, sv = 0.f;
#pragma unroll
    for (int i2 = 0; i2 < 16; ++i2) {
        float v = (float)phrow[i2];
        sh += __expf(v * t1 - mh);
        sv += __expf(v * t2 - mv);
    }
    redA[tid] = sh; redB[tid] = sv;
    __syncthreads();
    if (tid < 64) {
        float ash = 0.f, asv = 0.f;
#pragma unroll
        for (int q2 = 0; q2 < 16; ++q2) { ash += redA[q2 * 64 + tid]; asv += redB[q2 * 64 + tid]; }
        rHs[tid] = 1.f / ash;
        rVs[tid] = 1.f / asv;
    }
    __syncthreads();
    float rh = rHs[r_], rv = rVs[r_];
#pragma unroll
    for (int i2 = 0; i2 < 16; ++i2) {
        float v = (float)phrow[i2];
        phrow[i2] = (half_t)(__expf(v * t1 - mh) * rh);
        pvrow[i2] = (half_t)(__expf(v * t2 - mv) * rv);
    }
    __syncthreads();

    // ---- pass 2: x = P_H@V_H + P_V@V_V. wave w owns d-chunks w*64, w*64+1024 ----
#pragma unroll
    for (int i2 = 0; i2 < 2; ++i2) {
        int d0 = wave * 64 + i2 * 1024;
        f32x4 acc2[4][4];
#pragma unroll
        for (int a = 0; a < 4; ++a)
#pragma unroll
            for (int c = 0; c < 4; ++c) acc2[a][c] = {0.f, 0.f, 0.f, 0.f};
        __builtin_amdgcn_s_setprio(1);
        for (int kc = 0; kc < 8; ++kc) {
            int tk = kc * 32 + quad * 8;
            half8 afr[4];
#pragma unroll
            for (int mt = 0; mt < 4; ++mt)
                afr[mt] = *(const half8*)&PH[(mt * 16 + l15) * 264 + tk];
#pragma unroll
            for (int nt = 0; nt < 4; ++nt) {
                half8 bfr = *(const half8*)(VHb + (size_t)(d0 + nt * 16 + l15) * 256 + tk);
#pragma unroll
                for (int mt = 0; mt < 4; ++mt)
                    acc2[mt][nt] = __builtin_amdgcn_mfma_f32_16x16x32_f16(afr[mt], bfr, acc2[mt][nt], 0, 0, 0);
            }
#pragma unroll
            for (int mt = 0; mt < 4; ++mt)
                afr[mt] = *(const half8*)&PV[(mt * 16 + l15) * 264 + tk];
#pragma unroll
            for (int nt = 0; nt < 4; ++nt) {
                half8 bfr = *(const half8*)(VVb + (size_t)(d0 + nt * 16 + l15) * 256 + tk);
#pragma unroll
                for (int mt = 0; mt < 4; ++mt)
                    acc2[mt][nt] = __builtin_amdgcn_mfma_f32_16x16x32_f16(afr[mt], bfr, acc2[mt][nt], 0, 0, 0);
            }
        }
        __builtin_amdgcn_s_setprio(0);
        int db = wave + i2 * 16;   // d0/64 in [0,32)
#pragma unroll
        for (int mt = 0; mt < 4; ++mt)
#pragma unroll
            for (int nt = 0; nt < 4; ++nt) {
                int c = nt * 16 + l15;
#pragma unroll
                for (int r = 0; r < 4; ++r) {
                    int srow = mt * 16 + quad * 4 + r;
                    size_t tk_idx = (size_t)b * 65536 + (size_t)(sq0 + srow) * 256 + h * 32 + db;
                    xhv[tk_idx * 64 + c] = (half_t)acc2[mt][nt][r];
                }
            }
    }
}

// ---------------- C: out = xhv @ proj_w.T + proj_b ----------------
__global__ __launch_bounds__(256) void kC(const half_t* __restrict__ xhv, const half_t* __restrict__ Wp,
                                          const float* __restrict__ proj_b, float* __restrict__ out) {
    __shared__ float ot[64 * 68];
    int tid = threadIdx.x, wave = tid >> 6, lane = tid & 63;
    int l15 = lane & 15, quad = lane >> 4;
    size_t T0 = (size_t)blockIdx.x * 64;
    f32x4 acc[4];
#pragma unroll
    for (int a = 0; a < 4; ++a) acc[a] = {0.f, 0.f, 0.f, 0.f};
#pragma unroll
    for (int kc = 0; kc < 2; ++kc) {
        int c = kc * 32 + quad * 8;
        half8 bfr = *(const half8*)(Wp + (wave * 16 + l15) * 64 + c);
#pragma unroll
        for (int mt = 0; mt < 4; ++mt) {
            half8 afr = *(const half8*)(xhv + (T0 + mt * 16 + l15) * 64 + c);
            acc[mt] = __builtin_amdgcn_mfma_f32_16x16x32_f16(afr, bfr, acc[mt], 0, 0, 0);
        }
    }
    float bj = proj_b[wave * 16 + l15];
#pragma unroll
    for (int mt = 0; mt < 4; ++mt)
#pragma unroll
        for (int r = 0; r < 4; ++r)
            ot[(mt * 16 + quad * 4 + r) * 68 + wave * 16 + l15] = acc[mt][r] + bj;
    __syncthreads();
    int row = tid >> 2;
#pragma unroll
    for (int u = 0; u < 4; ++u) {
        int col = (tid & 3) * 4 + u * 16;
        f32x4 v = *(const f32x4*)&ot[row * 68 + col];
        *(f32x4*)(out + (T0 + row) * 64 + col) = v;
    }
}

extern "C" void kernel_launch(void* const* d_in, const int* in_sizes, int n_in,
                              void* d_out, int out_size, void* d_ws, size_t ws_size,
                              hipStream_t stream) {
    const float* x      = (const float*)d_in[0];
    const float* qkv_w  = (const float*)d_in[1];
    const float* qkv_b  = (const float*)d_in[2];
    const float* proj_w = (const float*)d_in[3];
    const float* proj_b = (const float*)d_in[4];
    const float* temp1  = (const float*)d_in[5];
    const float* temp2  = (const float*)d_in[6];
    char* ws = (char*)d_ws;
    half_t* Q   = (half_t*)(ws + WS_Q);
    half_t* K   = (half_t*)(ws + WS_K);
    half_t* VH  = (half_t*)(ws + WS_VH);
    half_t* VV  = (half_t*)(ws + WS_VV);
    half_t* xhv = (half_t*)(ws + WS_XHV);
    float* normQ = (float*)(ws + WS_NQ);
    float* normK = (float*)(ws + WS_NK);
    half_t* Wh  = (half_t*)(ws + WS_WH);
    half_t* Wp  = (half_t*)(ws + WS_WP);
    float* out = (float*)d_out;

    hipFuncSetAttribute((const void*)kB, hipFuncAttributeMaxDynamicSharedMemorySize, 160000);

    kW0<<<1, 256, 0, stream>>>(qkv_w, proj_w, Wh, Wp);
    kA1<<<4096, 256, 0, stream>>>(x, Wh, qkv_b, Q, K, normQ, normK);
    kA2H<<<2048, 256, 0, stream>>>(x, Wh, qkv_b, VH);
    kA2V<<<2048, 256, 0, stream>>>(x, Wh, qkv_b, VV);
    kB<<<256, 1024, 160000, stream>>>(Q, K, VH, VV, normQ, normK, temp1, temp2, xhv);
    kC<<<8192, 256, 0, stream>>>(xhv, Wp, proj_b, out);
}

// Round 5
// 590.785 us; speedup vs baseline: 1.0555x; 1.0555x over previous
//
#include <hip/hip_runtime.h>

// EDTAttention MI355X, round 7: kill kB's 3.1x xhv write amplification.
// xhv re-laid out as [b][h][db][s][c] so each kB wave's (i2,db) output is a
// contiguous 8KB run; epilogue dumps acc2 to per-wave LDS scratch (dead
// pass-1 staging region, double-buffered per mt) then stores half8 full
// lines. kC reads the new layout (scattered 128B full-line reads, no RMW).
// Softmax = round-3 shuffle version (verified): -4 barriers, -8KB LDS.
// setprio removed (neutral in round-4 A/B).
//
// Index algebra (verified in earlier rounds):
//   Y[b,t,j] = xf @ qkv_w.T + qkv_b,  t = s*256+n, j in [0,256)
//   Q[b,h,s,d]  = Y[b, s*256 +       h*8+ns, j]   d = ns*256+j
//   K[b,h,s,d]  = Y[b, s*256 +  64 + h*8+ns, j]
//   VH[b,h,s,d] = Y[b, s*256 + 128 + h*8+ns, j]
//   VV[b,h,t,d] = Y[b, (h*32+d/64)*256 + 192 + (t/32)*8 + (t%32)/4, (t%4)*64 + d%64]
//   xhv2[(((b*8+h)*32+db)*256 + s)*64 + c] holds attention output for
//   token (b,s,n=h*32+db), channel c.

using half_t = _Float16;
using half8 = __attribute__((ext_vector_type(8))) _Float16;
using f32x4 = __attribute__((ext_vector_type(4))) float;

#define NTOK 524288      // 8*256*256

// async global->LDS, 16B per lane, LDS dest = wave-uniform base + lane*16
#define GLDS(g, l) __builtin_amdgcn_global_load_lds( \
    (const __attribute__((address_space(1))) void*)(g), \
    (__attribute__((address_space(3))) void*)(l), 16, 0, 0)

// ---- workspace layout (bytes) ----
#define WS_Q      0
#define WS_K      67108864
#define WS_VH     134217728
#define WS_VV     201326592
#define WS_XHV    268435456
#define WS_NQ     335544320
#define WS_NK     335609856
#define WS_WH     335675392
#define WS_WP     335708160

// ---------------- weight prep: fp32 -> f16 ----------------
__global__ void kW0(const float* __restrict__ qkv_w, const float* __restrict__ proj_w,
                    half_t* __restrict__ Wh, half_t* __restrict__ Wp) {
    int tid = threadIdx.x;
    for (int i = tid; i < 256 * 64; i += 256) Wh[i] = (half_t)qkv_w[i];
    for (int i = tid; i < 64 * 64; i += 256) Wp[i] = (half_t)proj_w[i];
}

// ---------------- Y-tile MFMA core: acc[mt][i] over 64 tokens x 256 j, K=64 ----
__device__ inline void y_tile_mfma(const float* __restrict__ xb,
                                   const half_t* __restrict__ Wh,
                                   int tbase, int hi, int lo,
                                   f32x4 (&acc)[4][4], int wave, int lane) {
    const int l15 = lane & 15, quad = lane >> 4;
#pragma unroll
    for (int kc = 0; kc < 2; ++kc) {
        const int c = kc * 32 + quad * 8;
        half8 afr[4];
#pragma unroll
        for (int mt = 0; mt < 4; ++mt) {
            int m = mt * 16 + l15;
            int token = tbase + (m >> 3) * hi + (m & 7) * lo;
            const float* p = xb + (size_t)token * 64 + c;
            f32x4 f0 = *(const f32x4*)p;
            f32x4 f1 = *(const f32x4*)(p + 4);
            half8 a;
            a[0] = (half_t)f0[0]; a[1] = (half_t)f0[1]; a[2] = (half_t)f0[2]; a[3] = (half_t)f0[3];
            a[4] = (half_t)f1[0]; a[5] = (half_t)f1[1]; a[6] = (half_t)f1[2]; a[7] = (half_t)f1[3];
            afr[mt] = a;
        }
#pragma unroll
        for (int i = 0; i < 4; ++i) {
            int j = (wave * 4 + i) * 16 + l15;
            half8 bfr = *(const half8*)(Wh + j * 64 + c);
#pragma unroll
            for (int mt = 0; mt < 4; ++mt)
                acc[mt][i] = __builtin_amdgcn_mfma_f32_16x16x32_f16(afr[mt], bfr, acc[mt][i], 0, 0, 0);
        }
    }
}

// row-major dump: ylds[m][j], stride 264
__device__ inline void y_dump_rowmajor(f32x4 (&acc)[4][4], const float* __restrict__ qkv_b,
                                       half_t* ylds, int wave, int lane) {
    const int l15 = lane & 15, quad = lane >> 4;
#pragma unroll
    for (int i = 0; i < 4; ++i) {
        int j = (wave * 4 + i) * 16 + l15;
        float bj = qkv_b[j];
#pragma unroll
        for (int mt = 0; mt < 4; ++mt)
#pragma unroll
            for (int r = 0; r < 4; ++r)
                ylds[(mt * 16 + quad * 4 + r) * 264 + j] = (half_t)(acc[mt][i][r] + bj);
    }
}

// transposed dump: yldsT[j][m], stride 72
__device__ inline void y_dump_transposed(f32x4 (&acc)[4][4], const float* __restrict__ qkv_b,
                                         half_t* yldsT, int wave, int lane) {
    const int l15 = lane & 15, quad = lane >> 4;
#pragma unroll
    for (int i = 0; i < 4; ++i) {
        int j = (wave * 4 + i) * 16 + l15;
        float bj = qkv_b[j];
#pragma unroll
        for (int mt = 0; mt < 4; ++mt)
#pragma unroll
            for (int r = 0; r < 4; ++r)
                yldsT[j * 72 + mt * 16 + quad * 4 + r] = (half_t)(acc[mt][i][r] + bj);
    }
}

// ---------------- A1: Q and K (g=0,1) + norms ----------------
__global__ __launch_bounds__(256) void kA1(const float* __restrict__ x,
                                           const half_t* __restrict__ Wh,
                                           const float* __restrict__ qkv_b,
                                           half_t* __restrict__ Q, half_t* __restrict__ K,
                                           float* __restrict__ normQ, float* __restrict__ normK) {
    __shared__ half_t ylds[64 * 264];
    __shared__ float scr[256];
    int idx = blockIdx.x;
    int sb = idx & 31; idx >>= 5;
    int h = idx & 7; idx >>= 3;
    int g = idx & 1; int b = idx >> 1;
    int s0 = sb * 8;
    int n0 = g * 64 + h * 8;
    int tid = threadIdx.x, wave = tid >> 6, lane = tid & 63;
    const float* xb = x + (size_t)b * 65536 * 64;
    f32x4 acc[4][4];
#pragma unroll
    for (int a = 0; a < 4; ++a)
#pragma unroll
        for (int c = 0; c < 4; ++c) acc[a][c] = {0.f, 0.f, 0.f, 0.f};
    y_tile_mfma(xb, Wh, s0 * 256 + n0, 256, 1, acc, wave, lane);
    y_dump_rowmajor(acc, qkv_b, ylds, wave, lane);
    __syncthreads();
    half_t* dst = (g == 0 ? Q : K) + ((size_t)(b * 8 + h) * 256 + s0) * 2048;
    int ns = tid >> 5, jc = (tid & 31) * 8;
#pragma unroll
    for (int si = 0; si < 8; ++si) {
        half8 v = *(const half8*)&ylds[(si * 8 + ns) * 264 + jc];
        *(half8*)(dst + (size_t)si * 2048 + ns * 256 + jc) = v;
    }
    float sum = 0.f;
#pragma unroll
    for (int nn = 0; nn < 8; ++nn) {
        half8 v = *(const half8*)&ylds[((tid >> 5) * 8 + nn) * 264 + (tid & 31) * 8];
#pragma unroll
        for (int e = 0; e < 8; ++e) { float f = (float)v[e]; sum += f * f; }
    }
    scr[tid] = sum;
    __syncthreads();
    if (tid < 8) {
        float s = 0.f;
        for (int k2 = 0; k2 < 32; ++k2) s += scr[tid * 32 + k2];
        float* nd = (g == 0 ? normQ : normK);
        nd[(b * 8 + h) * 256 + s0 + tid] = s;
    }
}

// ---------------- A2H: V_H (g=2) -> VH[bh][d][t], wide stores ----------------
__global__ __launch_bounds__(256) void kA2H(const float* __restrict__ x,
                                            const half_t* __restrict__ Wh,
                                            const float* __restrict__ qkv_b,
                                            half_t* __restrict__ VH) {
    __shared__ half_t yldsT[256 * 72];
    int idx = blockIdx.x;
    int sb = idx & 3; idx >>= 2;
    int nn = idx & 63; int b = idx >> 6;
    int h = nn >> 3, ns = nn & 7;
    int n = 128 + nn;
    int s0 = sb * 64;
    int tid = threadIdx.x, wave = tid >> 6, lane = tid & 63;
    const float* xb = x + (size_t)b * 65536 * 64;
    f32x4 acc[4][4];
#pragma unroll
    for (int a = 0; a < 4; ++a)
#pragma unroll
        for (int c = 0; c < 4; ++c) acc[a][c] = {0.f, 0.f, 0.f, 0.f};
    y_tile_mfma(xb, Wh, s0 * 256 + n, 2048, 256, acc, wave, lane);  // m == local s
    y_dump_transposed(acc, qkv_b, yldsT, wave, lane);
    __syncthreads();
    int jl = lane >> 3, tc = lane & 7;
    half_t* base = VH + ((size_t)(b * 8 + h) * 2048 + ns * 256) * 256 + s0 + tc * 8;
#pragma unroll
    for (int u = 0; u < 8; ++u) {
        int j = wave * 64 + u * 8 + jl;
        half8 v = *(const half8*)&yldsT[j * 72 + tc * 8];
        *(half8*)(base + (size_t)j * 256) = v;
    }
}

// ---------------- A2V: V_V (g=3) -> VV[bh][d][t], direct-permuted dump -------
__global__ __launch_bounds__(256) void kA2V(const float* __restrict__ x,
                                            const half_t* __restrict__ Wh,
                                            const float* __restrict__ qkv_b,
                                            half_t* __restrict__ VV) {
    __shared__ half_t vlds[64 * 264];            // [dm][t], row stride 264
    int idx = blockIdx.x;
    int st = idx & 255; int b = idx >> 8;
    int h = st >> 5;
    int tid = threadIdx.x, wave = tid >> 6, lane = tid & 63;
    const float* xb = x + (size_t)b * 65536 * 64;
    f32x4 acc[4][4];
#pragma unroll
    for (int a = 0; a < 4; ++a)
#pragma unroll
        for (int c = 0; c < 4; ++c) acc[a][c] = {0.f, 0.f, 0.f, 0.f};
    y_tile_mfma(xb, Wh, st * 256 + 192, 8, 1, acc, wave, lane);  // m == n-192
    {
        const int l15 = lane & 15, quad = lane >> 4;
#pragma unroll
        for (int i = 0; i < 4; ++i) {
            int j = (wave * 4 + i) * 16 + l15;
            float bj = qkv_b[j];
            int dm = j & 63;
            int jc = j >> 6;
#pragma unroll
            for (int mt = 0; mt < 4; ++mt)
#pragma unroll
                for (int r = 0; r < 4; ++r) {
                    int m = mt * 16 + quad * 4 + r;
                    int t = 32 * (m >> 3) + 4 * (m & 7) + jc;
                    vlds[dm * 264 + t] = (half_t)(acc[mt][i][r] + bj);
                }
        }
    }
    __syncthreads();
    half_t* base = VV + ((size_t)(b * 8 + h) * 2048 + (st & 31) * 64) * 256;
    int l31 = lane & 31, lh = lane >> 5;
#pragma unroll
    for (int u = 0; u < 8; ++u) {
        int dm = u * 8 + wave * 2 + lh;
        half8 v = *(const half8*)&vlds[dm * 264 + l31 * 8];
        *(half8*)(base + (size_t)dm * 256 + l31 * 8) = v;
    }
}

// ---------------- B: fused cosine attention, QBLK=64, 256 blocks x 1024 thr ----
// Pass 1 = LDS-staged double-buffered GEMM. Softmax = 16-lane shuffle.
// Epilogue = per-wave LDS-staged full-line writes to xhv2[b][h][db][s][c].
__global__ __launch_bounds__(1024, 4) void kB(const half_t* __restrict__ Q, const half_t* __restrict__ K,
                                              const half_t* __restrict__ VH, const half_t* __restrict__ VV,
                                              const float* __restrict__ normQ, const float* __restrict__ normK,
                                              const float* __restrict__ temp1, const float* __restrict__ temp2,
                                              half_t* __restrict__ xhv) {
    extern __shared__ char smem[];
    char* Ks0 = smem;                            // [256][64] halfs, 32768B (pass-1 only)
    char* Ks1 = smem + 32768;                    // 32768B (pass-1 only)
    char* Qs0 = smem + 65536;                    // [64][64] halfs, 8192B (pass-1 only)
    char* Qs1 = smem + 73728;                    // 8192B (pass-1 only)
    half_t* PH = (half_t*)(smem + 81920);        // [64][264]
    half_t* PV = (half_t*)(smem + 115712);       // [64][264] -> 149504
    float* rq  = (float*)(smem + 149504);        // [64]
    float* rk  = (float*)(smem + 149760);        // [256] -> end 150784

    int idx = blockIdx.x;
    int bh = idx & 63;              // XCD swizzle: same-bh sq-siblings share XCD
    int sqb = idx >> 6;             // 0..3
    int h = bh & 7, b = bh >> 3;
    int sq0 = sqb * 64;
    int tid = threadIdx.x, wave = tid >> 6, lane = tid & 63;
    int l15 = lane & 15, quad = lane >> 4;
    float t1 = temp1[h], t2 = temp2[h];
    const half_t* Qb = Q + (size_t)bh * 256 * 2048;
    const half_t* Kb = K + (size_t)bh * 256 * 2048;
    const half_t* VHb = VH + (size_t)bh * 2048 * 256;
    const half_t* VVb = VV + (size_t)bh * 2048 * 256;

    if (tid < 64) rq[tid] = 1.f / fmaxf(sqrtf(normQ[bh * 256 + sq0 + tid]), 1e-12f);
    if (tid < 256) rk[tid] = 1.f / fmaxf(sqrtf(normK[bh * 256 + tid]), 1e-12f);

    // ---- pass 1: sim = Q.K^T (64 x 256), LDS-staged. wave w owns t-tile w*16 ----
    {
        const int l7 = lane & 7, l8 = lane >> 3;
        // pre-swizzled global source: LDS slot (row r, s) holds global col16 s^(r&7).
        const int swzh = (l7 ^ (l8 & 7)) * 8;     // halfs offset within 64-half row
        const half_t* gK0 = Kb + (size_t)(wave * 8 + l8) * 2048 + swzh;         // rows [w*8, +8)
        const half_t* gK1 = Kb + (size_t)(128 + wave * 8 + l8) * 2048 + swzh;   // rows [128+w*8, +8)
        const half_t* gQ  = Qb + (size_t)(sq0 + (wave & 7) * 8 + l8) * 2048 + swzh;

        auto STAGE = [&](int kk, char* KsB, char* QsB) {
            const int off = kk * 64;              // BK=64 halfs per step
            GLDS(gK0 + off, KsB + wave * 1024);
            GLDS(gK1 + off, KsB + 16384 + wave * 1024);
            if (wave < 8) GLDS(gQ + off, QsB + wave * 1024);
        };

        f32x4 acc1[4];
#pragma unroll
        for (int a = 0; a < 4; ++a) acc1[a] = {0.f, 0.f, 0.f, 0.f};
        const int tcol = wave * 16 + l15;
        const int ts7 = tcol & 7;

        auto COMPUTE = [&](const char* KsB_, const char* QsB_) {
            const half_t* KsB = (const half_t*)KsB_;
            const half_t* QsB = (const half_t*)QsB_;
#pragma unroll
            for (int sub = 0; sub < 2; ++sub) {
                int c16 = sub * 4 + quad;         // 16B-slot index = d-slice
                half8 bfr = *(const half8*)(KsB + tcol * 64 + (c16 ^ ts7) * 8);
#pragma unroll
                for (int mt = 0; mt < 4; ++mt) {
                    int m = mt * 16 + l15;
                    half8 afr = *(const half8*)(QsB + m * 64 + (c16 ^ (m & 7)) * 8);
                    acc1[mt] = __builtin_amdgcn_mfma_f32_16x16x32_f16(afr, bfr, acc1[mt], 0, 0, 0);
                }
            }
        };

        STAGE(0, Ks0, Qs0);
        __syncthreads();                          // drains vmcnt -> buf0 ready (also rq/rk)
        for (int kk = 0; kk < 32; kk += 2) {
            if (kk + 1 < 32) STAGE(kk + 1, Ks1, Qs1);
            COMPUTE(Ks0, Qs0);
            __syncthreads();                      // buf1 staged + buf0 consumed
            if (kk + 2 < 32) STAGE(kk + 2, Ks0, Qs0);
            COMPUTE(Ks1, Qs1);
            __syncthreads();
        }
        float rkt = rk[tcol];
#pragma unroll
        for (int mt = 0; mt < 4; ++mt)
#pragma unroll
            for (int r = 0; r < 4; ++r) {
                int row = mt * 16 + quad * 4 + r;
                PH[row * 264 + tcol] = (half_t)(acc1[mt][r] * rq[row] * rkt);
            }
    }
    __syncthreads();

    // ---- dual softmax: thread owns (row = tid>>4, chunk = tid&15); the 16
    // reducers of a row are contiguous lanes -> pure shuffle reduction ----
    {
        int r_ = tid >> 4, cc = tid & 15;
        half_t* phrow = &PH[r_ * 264 + cc * 16];
        half_t* pvrow = &PV[r_ * 264 + cc * 16];
        half8 v0 = *(const half8*)phrow;
        half8 v1 = *(const half8*)(phrow + 8);
        float fv[16];
#pragma unroll
        for (int e = 0; e < 8; ++e) { fv[e] = (float)v0[e]; fv[8 + e] = (float)v1[e]; }
        float mx = fv[0], mn = fv[0];
#pragma unroll
        for (int e = 1; e < 16; ++e) { mx = fmaxf(mx, fv[e]); mn = fminf(mn, fv[e]); }
#pragma unroll
        for (int m = 1; m < 16; m <<= 1) {
            mx = fmaxf(mx, __shfl_xor(mx, m, 16));
            mn = fminf(mn, __shfl_xor(mn, m, 16));
        }
        float mh = (t1 >= 0.f) ? t1 * mx : t1 * mn;
        float mv = (t2 >= 0.f) ? t2 * mx : t2 * mn;
        float sh = 0.f, sv = 0.f;
#pragma unroll
        for (int e = 0; e < 16; ++e) {
            sh += __expf(fv[e] * t1 - mh);
            sv += __expf(fv[e] * t2 - mv);
        }
#pragma unroll
        for (int m = 1; m < 16; m <<= 1) {
            sh += __shfl_xor(sh, m, 16);
            sv += __shfl_xor(sv, m, 16);
        }
        float rh = 1.f / sh, rv = 1.f / sv;
        half8 o0, o1, p0, p1;
#pragma unroll
        for (int e = 0; e < 8; ++e) {
            o0[e] = (half_t)(__expf(fv[e] * t1 - mh) * rh);
            o1[e] = (half_t)(__expf(fv[8 + e] * t1 - mh) * rh);
            p0[e] = (half_t)(__expf(fv[e] * t2 - mv) * rv);
            p1[e] = (half_t)(__expf(fv[8 + e] * t2 - mv) * rv);
        }
        *(half8*)phrow = o0; *(half8*)(phrow + 8) = o1;
        *(half8*)pvrow = p0; *(half8*)(pvrow + 8) = p1;
    }
    __syncthreads();

    // ---- pass 2: x = P_H@V_H + P_V@V_V. wave w owns d-chunks w*64, w*64+1024.
    // Epilogue: acc2 -> per-wave LDS scratch (dead staging region, 2 slices)
    // -> half8 full-line stores, 8KB contiguous per (i2). ----
    const int rr = lane >> 3, c8 = (lane & 7) * 8;
#pragma unroll
    for (int i2 = 0; i2 < 2; ++i2) {
        int d0 = wave * 64 + i2 * 1024;
        f32x4 acc2[4][4];
#pragma unroll
        for (int a = 0; a < 4; ++a)
#pragma unroll
            for (int c = 0; c < 4; ++c) acc2[a][c] = {0.f, 0.f, 0.f, 0.f};
        for (int kc = 0; kc < 8; ++kc) {
            int tk = kc * 32 + quad * 8;
            half8 afr[4];
#pragma unroll
            for (int mt = 0; mt < 4; ++mt)
                afr[mt] = *(const half8*)&PH[(mt * 16 + l15) * 264 + tk];
#pragma unroll
            for (int nt = 0; nt < 4; ++nt) {
                half8 bfr = *(const half8*)(VHb + (size_t)(d0 + nt * 16 + l15) * 256 + tk);
#pragma unroll
                for (int mt = 0; mt < 4; ++mt)
                    acc2[mt][nt] = __builtin_amdgcn_mfma_f32_16x16x32_f16(afr[mt], bfr, acc2[mt][nt], 0, 0, 0);
            }
#pragma unroll
            for (int mt = 0; mt < 4; ++mt)
                afr[mt] = *(const half8*)&PV[(mt * 16 + l15) * 264 + tk];
#pragma unroll
            for (int nt = 0; nt < 4; ++nt) {
                half8 bfr = *(const half8*)(VVb + (size_t)(d0 + nt * 16 + l15) * 256 + tk);
#pragma unroll
                for (int mt = 0; mt < 4; ++mt)
                    acc2[mt][nt] = __builtin_amdgcn_mfma_f32_16x16x32_f16(afr[mt], bfr, acc2[mt][nt], 0, 0, 0);
            }
        }
        int db = wave + i2 * 16;   // d0/64 in [0,32)
        half_t* xbase = xhv + (((size_t)(b * 8 + h) * 32 + db) * 256 + sq0) * 64;
#pragma unroll
        for (int mt = 0; mt < 4; ++mt) {
            // double-buffered per-wave scratch: 2 x 2560B slices within 5120B
            half_t* myscr = (half_t*)(smem + wave * 5120 + (mt & 1) * 2560);
#pragma unroll
            for (int nt = 0; nt < 4; ++nt)
#pragma unroll
                for (int r = 0; r < 4; ++r)
                    myscr[(quad * 4 + r) * 72 + nt * 16 + l15] = (half_t)acc2[mt][nt][r];
#pragma unroll
            for (int u = 0; u < 2; ++u) {
                half8 v = *(const half8*)&myscr[(u * 8 + rr) * 72 + c8];
                *(half8*)(xbase + (size_t)(mt * 16 + u * 8 + rr) * 64 + c8) = v;
            }
        }
    }
}

// ---------------- C: out = xhv2 @ proj_w.T + proj_b ----------------
__global__ __launch_bounds__(256) void kC(const half_t* __restrict__ xhv, const half_t* __restrict__ Wp,
                                          const float* __restrict__ proj_b, float* __restrict__ out) {
    __shared__ float ot[64 * 68];
    int tid = threadIdx.x, wave = tid >> 6, lane = tid & 63;
    int l15 = lane & 15, quad = lane >> 4;
    size_t T0 = (size_t)blockIdx.x * 64;
    int b = (int)(T0 >> 16);
    int s = (int)((T0 >> 8) & 255);
    int n0 = (int)(T0 & 255);
    f32x4 acc[4];
#pragma unroll
    for (int a = 0; a < 4; ++a) acc[a] = {0.f, 0.f, 0.f, 0.f};
#pragma unroll
    for (int kc = 0; kc < 2; ++kc) {
        int c = kc * 32 + quad * 8;
        half8 bfr = *(const half8*)(Wp + (wave * 16 + l15) * 64 + c);
#pragma unroll
        for (int mt = 0; mt < 4; ++mt) {
            int n = n0 + mt * 16 + l15;
            int hh = n >> 5, db = n & 31;
            const half_t* arow = xhv + (((size_t)(b * 8 + hh) * 32 + db) * 256 + s) * 64;
            half8 afr = *(const half8*)(arow + c);
            acc[mt] = __builtin_amdgcn_mfma_f32_16x16x32_f16(afr, bfr, acc[mt], 0, 0, 0);
        }
    }
    float bj = proj_b[wave * 16 + l15];
#pragma unroll
    for (int mt = 0; mt < 4; ++mt)
#pragma unroll
        for (int r = 0; r < 4; ++r)
            ot[(mt * 16 + quad * 4 + r) * 68 + wave * 16 + l15] = acc[mt][r] + bj;
    __syncthreads();
    int row = tid >> 2;
#pragma unroll
    for (int u = 0; u < 4; ++u) {
        int col = (tid & 3) * 4 + u * 16;
        f32x4 v = *(const f32x4*)&ot[row * 68 + col];
        *(f32x4*)(out + (T0 + row) * 64 + col) = v;
    }
}

extern "C" void kernel_launch(void* const* d_in, const int* in_sizes, int n_in,
                              void* d_out, int out_size, void* d_ws, size_t ws_size,
                              hipStream_t stream) {
    const float* x      = (const float*)d_in[0];
    const float* qkv_w  = (const float*)d_in[1];
    const float* qkv_b  = (const float*)d_in[2];
    const float* proj_w = (const float*)d_in[3];
    const float* proj_b = (const float*)d_in[4];
    const float* temp1  = (const float*)d_in[5];
    const float* temp2  = (const float*)d_in[6];
    char* ws = (char*)d_ws;
    half_t* Q   = (half_t*)(ws + WS_Q);
    half_t* K   = (half_t*)(ws + WS_K);
    half_t* VH  = (half_t*)(ws + WS_VH);
    half_t* VV  = (half_t*)(ws + WS_VV);
    half_t* xhv = (half_t*)(ws + WS_XHV);
    float* normQ = (float*)(ws + WS_NQ);
    float* normK = (float*)(ws + WS_NK);
    half_t* Wh  = (half_t*)(ws + WS_WH);
    half_t* Wp  = (half_t*)(ws + WS_WP);
    float* out = (float*)d_out;

    hipFuncSetAttribute((const void*)kB, hipFuncAttributeMaxDynamicSharedMemorySize, 150784);

    kW0<<<1, 256, 0, stream>>>(qkv_w, proj_w, Wh, Wp);
    kA1<<<4096, 256, 0, stream>>>(x, Wh, qkv_b, Q, K, normQ, normK);
    kA2H<<<2048, 256, 0, stream>>>(x, Wh, qkv_b, VH);
    kA2V<<<2048, 256, 0, stream>>>(x, Wh, qkv_b, VV);
    kB<<<256, 1024, 150784, stream>>>(Q, K, VH, VV, normQ, normK, temp1, temp2, xhv);
    kC<<<8192, 256, 0, stream>>>(xhv, Wp, proj_b, out);
}

// Round 6
// 586.267 us; speedup vs baseline: 1.0637x; 1.0077x over previous
//
#include <hip/hip_runtime.h>

// EDTAttention MI355X, round 8:
// (1) kB pass-1: 3-buffer 2-deep pipeline, raw s_barrier + counted
//     s_waitcnt vmcnt(L) (never drain to 0 in the loop - T4). PH/PV overlap
//     dead staging buffers; pass-2 scratch lives in dead buf2. 1 barrier/step.
// (2) kA1: swapped MFMA operands (D^T: row=j, col=token) -> packed half4
//     rowmajor dump (16 vs 64 LDS writes/lane). Downstream reads unchanged.
// (3) kA2H: packed half4 transposed dump (4 consecutive m at fixed j).
//
// Index algebra (verified in earlier rounds):
//   Y[b,t,j] = xf @ qkv_w.T + qkv_b,  t = s*256+n, j in [0,256)
//   Q[b,h,s,d]  = Y[b, s*256 +       h*8+ns, j]   d = ns*256+j
//   K[b,h,s,d]  = Y[b, s*256 +  64 + h*8+ns, j]
//   VH[b,h,s,d] = Y[b, s*256 + 128 + h*8+ns, j]
//   VV[b,h,t,d] = Y[b, (h*32+d/64)*256 + 192 + (t/32)*8 + (t%32)/4, (t%4)*64 + d%64]
//   xhv2[(((b*8+h)*32+db)*256 + s)*64 + c] = attn out for token (b,s,n=h*32+db).

using half_t = _Float16;
using half4 = __attribute__((ext_vector_type(4))) _Float16;
using half8 = __attribute__((ext_vector_type(8))) _Float16;
using f32x4 = __attribute__((ext_vector_type(4))) float;

#define NTOK 524288      // 8*256*256

// async global->LDS, 16B per lane, LDS dest = wave-uniform base + lane*16
#define GLDS(g, l) __builtin_amdgcn_global_load_lds( \
    (const __attribute__((address_space(1))) void*)(g), \
    (__attribute__((address_space(3))) void*)(l), 16, 0, 0)

// ---- workspace layout (bytes) ----
#define WS_Q      0
#define WS_K      67108864
#define WS_VH     134217728
#define WS_VV     201326592
#define WS_XHV    268435456
#define WS_NQ     335544320
#define WS_NK     335609856
#define WS_WH     335675392
#define WS_WP     335708160

// ---------------- weight prep: fp32 -> f16 ----------------
__global__ void kW0(const float* __restrict__ qkv_w, const float* __restrict__ proj_w,
                    half_t* __restrict__ Wh, half_t* __restrict__ Wp) {
    int tid = threadIdx.x;
    for (int i = tid; i < 256 * 64; i += 256) Wh[i] = (half_t)qkv_w[i];
    for (int i = tid; i < 64 * 64; i += 256) Wp[i] = (half_t)proj_w[i];
}

// ---------------- Y-tile MFMA core (original orientation): acc[mt][i] ---------
__device__ inline void y_tile_mfma(const float* __restrict__ xb,
                                   const half_t* __restrict__ Wh,
                                   int tbase, int hi, int lo,
                                   f32x4 (&acc)[4][4], int wave, int lane) {
    const int l15 = lane & 15, quad = lane >> 4;
#pragma unroll
    for (int kc = 0; kc < 2; ++kc) {
        const int c = kc * 32 + quad * 8;
        half8 afr[4];
#pragma unroll
        for (int mt = 0; mt < 4; ++mt) {
            int m = mt * 16 + l15;
            int token = tbase + (m >> 3) * hi + (m & 7) * lo;
            const float* p = xb + (size_t)token * 64 + c;
            f32x4 f0 = *(const f32x4*)p;
            f32x4 f1 = *(const f32x4*)(p + 4);
            half8 a;
            a[0] = (half_t)f0[0]; a[1] = (half_t)f0[1]; a[2] = (half_t)f0[2]; a[3] = (half_t)f0[3];
            a[4] = (half_t)f1[0]; a[5] = (half_t)f1[1]; a[6] = (half_t)f1[2]; a[7] = (half_t)f1[3];
            afr[mt] = a;
        }
#pragma unroll
        for (int i = 0; i < 4; ++i) {
            int j = (wave * 4 + i) * 16 + l15;
            half8 bfr = *(const half8*)(Wh + j * 64 + c);
#pragma unroll
            for (int mt = 0; mt < 4; ++mt)
                acc[mt][i] = __builtin_amdgcn_mfma_f32_16x16x32_f16(afr[mt], bfr, acc[mt][i], 0, 0, 0);
        }
    }
}

// ---------------- Y-tile MFMA, SWAPPED operands: acc[i][mt], D^T --------------
// D[row=j_local, col=token]: row = quad*4+r within j-16-block, col = l15.
// Enables packed half4 rowmajor dump (4 consecutive j at fixed token).
__device__ inline void y_tile_mfma_swapped(const float* __restrict__ xb,
                                           const half_t* __restrict__ Wh,
                                           int tbase, int hi, int lo,
                                           f32x4 (&acc)[4][4], int wave, int lane) {
    const int l15 = lane & 15, quad = lane >> 4;
#pragma unroll
    for (int kc = 0; kc < 2; ++kc) {
        const int c = kc * 32 + quad * 8;
        half8 bx[4];
#pragma unroll
        for (int mt = 0; mt < 4; ++mt) {
            int m = mt * 16 + l15;
            int token = tbase + (m >> 3) * hi + (m & 7) * lo;
            const float* p = xb + (size_t)token * 64 + c;
            f32x4 f0 = *(const f32x4*)p;
            f32x4 f1 = *(const f32x4*)(p + 4);
            half8 a;
            a[0] = (half_t)f0[0]; a[1] = (half_t)f0[1]; a[2] = (half_t)f0[2]; a[3] = (half_t)f0[3];
            a[4] = (half_t)f1[0]; a[5] = (half_t)f1[1]; a[6] = (half_t)f1[2]; a[7] = (half_t)f1[3];
            bx[mt] = a;
        }
#pragma unroll
        for (int i = 0; i < 4; ++i) {
            int j = (wave * 4 + i) * 16 + l15;
            half8 aw = *(const half8*)(Wh + j * 64 + c);
#pragma unroll
            for (int mt = 0; mt < 4; ++mt)
                acc[i][mt] = __builtin_amdgcn_mfma_f32_16x16x32_f16(aw, bx[mt], acc[i][mt], 0, 0, 0);
        }
    }
}

// transposed dump: yldsT[j][m], stride 72 (original orientation, scalar - kA2V)
__device__ inline void y_dump_transposed(f32x4 (&acc)[4][4], const float* __restrict__ qkv_b,
                                         half_t* yldsT, int wave, int lane) {
    const int l15 = lane & 15, quad = lane >> 4;
#pragma unroll
    for (int i = 0; i < 4; ++i) {
        int j = (wave * 4 + i) * 16 + l15;
        float bj = qkv_b[j];
#pragma unroll
        for (int mt = 0; mt < 4; ++mt)
#pragma unroll
            for (int r = 0; r < 4; ++r)
                yldsT[j * 72 + mt * 16 + quad * 4 + r] = (half_t)(acc[mt][i][r] + bj);
    }
}

// ---------------- A1: Q and K (g=0,1) + norms (swapped + packed dump) ---------
__global__ __launch_bounds__(256) void kA1(const float* __restrict__ x,
                                           const half_t* __restrict__ Wh,
                                           const float* __restrict__ qkv_b,
                                           half_t* __restrict__ Q, half_t* __restrict__ K,
                                           float* __restrict__ normQ, float* __restrict__ normK) {
    __shared__ half_t ylds[64 * 264];
    __shared__ float scr[256];
    int idx = blockIdx.x;
    int sb = idx & 31; idx >>= 5;
    int h = idx & 7; idx >>= 3;
    int g = idx & 1; int b = idx >> 1;
    int s0 = sb * 8;
    int n0 = g * 64 + h * 8;
    int tid = threadIdx.x, wave = tid >> 6, lane = tid & 63;
    const int l15 = lane & 15, quad = lane >> 4;
    const float* xb = x + (size_t)b * 65536 * 64;
    f32x4 acc[4][4];   // [i][mt]
#pragma unroll
    for (int a = 0; a < 4; ++a)
#pragma unroll
        for (int c = 0; c < 4; ++c) acc[a][c] = {0.f, 0.f, 0.f, 0.f};
    y_tile_mfma_swapped(xb, Wh, s0 * 256 + n0, 256, 1, acc, wave, lane);
    // packed rowmajor dump: per (i,mt): 4 consecutive j at token m -> half4
#pragma unroll
    for (int i = 0; i < 4; ++i) {
        int j0 = (wave * 4 + i) * 16 + quad * 4;
        f32x4 bj = *(const f32x4*)&qkv_b[j0];
#pragma unroll
        for (int mt = 0; mt < 4; ++mt) {
            int m = mt * 16 + l15;
            half4 v;
#pragma unroll
            for (int r = 0; r < 4; ++r) v[r] = (half_t)(acc[i][mt][r] + bj[r]);
            *(half4*)&ylds[m * 264 + j0] = v;
        }
    }
    __syncthreads();
    half_t* dst = (g == 0 ? Q : K) + ((size_t)(b * 8 + h) * 256 + s0) * 2048;
    int ns = tid >> 5, jc = (tid & 31) * 8;
#pragma unroll
    for (int si = 0; si < 8; ++si) {
        half8 v = *(const half8*)&ylds[(si * 8 + ns) * 264 + jc];
        *(half8*)(dst + (size_t)si * 2048 + ns * 256 + jc) = v;
    }
    float sum = 0.f;
#pragma unroll
    for (int nn = 0; nn < 8; ++nn) {
        half8 v = *(const half8*)&ylds[((tid >> 5) * 8 + nn) * 264 + (tid & 31) * 8];
#pragma unroll
        for (int e = 0; e < 8; ++e) { float f = (float)v[e]; sum += f * f; }
    }
    scr[tid] = sum;
    __syncthreads();
    if (tid < 8) {
        float s = 0.f;
        for (int k2 = 0; k2 < 32; ++k2) s += scr[tid * 32 + k2];
        float* nd = (g == 0 ? normQ : normK);
        nd[(b * 8 + h) * 256 + s0 + tid] = s;
    }
}

// ---------------- A2H: V_H (g=2) -> VH[bh][d][t], packed transposed dump ------
__global__ __launch_bounds__(256) void kA2H(const float* __restrict__ x,
                                            const half_t* __restrict__ Wh,
                                            const float* __restrict__ qkv_b,
                                            half_t* __restrict__ VH) {
    __shared__ half_t yldsT[256 * 72];
    int idx = blockIdx.x;
    int sb = idx & 3; idx >>= 2;
    int nn = idx & 63; int b = idx >> 6;
    int h = nn >> 3, ns = nn & 7;
    int n = 128 + nn;
    int s0 = sb * 64;
    int tid = threadIdx.x, wave = tid >> 6, lane = tid & 63;
    const int l15 = lane & 15, quad = lane >> 4;
    const float* xb = x + (size_t)b * 65536 * 64;
    f32x4 acc[4][4];
#pragma unroll
    for (int a = 0; a < 4; ++a)
#pragma unroll
        for (int c = 0; c < 4; ++c) acc[a][c] = {0.f, 0.f, 0.f, 0.f};
    y_tile_mfma(xb, Wh, s0 * 256 + n, 2048, 256, acc, wave, lane);  // m == local s
    // packed transposed dump: per (i,mt): 4 consecutive m at fixed j -> half4
#pragma unroll
    for (int i = 0; i < 4; ++i) {
        int j = (wave * 4 + i) * 16 + l15;
        float bj = qkv_b[j];
#pragma unroll
        for (int mt = 0; mt < 4; ++mt) {
            half4 v;
#pragma unroll
            for (int r = 0; r < 4; ++r) v[r] = (half_t)(acc[mt][i][r] + bj);
            *(half4*)&yldsT[j * 72 + mt * 16 + quad * 4] = v;
        }
    }
    __syncthreads();
    int jl = lane >> 3, tc = lane & 7;
    half_t* base = VH + ((size_t)(b * 8 + h) * 2048 + ns * 256) * 256 + s0 + tc * 8;
#pragma unroll
    for (int u = 0; u < 8; ++u) {
        int j = wave * 64 + u * 8 + jl;
        half8 v = *(const half8*)&yldsT[j * 72 + tc * 8];
        *(half8*)(base + (size_t)j * 256) = v;
    }
}

// ---------------- A2V: V_V (g=3) -> VV[bh][d][t], direct-permuted dump -------
__global__ __launch_bounds__(256) void kA2V(const float* __restrict__ x,
                                            const half_t* __restrict__ Wh,
                                            const float* __restrict__ qkv_b,
                                            half_t* __restrict__ VV) {
    __shared__ half_t vlds[64 * 264];            // [dm][t], row stride 264
    int idx = blockIdx.x;
    int st = idx & 255; int b = idx >> 8;
    int h = st >> 5;
    int tid = threadIdx.x, wave = tid >> 6, lane = tid & 63;
    const float* xb = x + (size_t)b * 65536 * 64;
    f32x4 acc[4][4];
#pragma unroll
    for (int a = 0; a < 4; ++a)
#pragma unroll
        for (int c = 0; c < 4; ++c) acc[a][c] = {0.f, 0.f, 0.f, 0.f};
    y_tile_mfma(xb, Wh, st * 256 + 192, 8, 1, acc, wave, lane);  // m == n-192
    {
        const int l15 = lane & 15, quad = lane >> 4;
#pragma unroll
        for (int i = 0; i < 4; ++i) {
            int j = (wave * 4 + i) * 16 + l15;
            float bj = qkv_b[j];
            int dm = j & 63;
            int jc = j >> 6;
#pragma unroll
            for (int mt = 0; mt < 4; ++mt)
#pragma unroll
                for (int r = 0; r < 4; ++r) {
                    int m = mt * 16 + quad * 4 + r;
                    int t = 32 * (m >> 3) + 4 * (m & 7) + jc;
                    vlds[dm * 264 + t] = (half_t)(acc[mt][i][r] + bj);
                }
        }
    }
    __syncthreads();
    half_t* base = VV + ((size_t)(b * 8 + h) * 2048 + (st & 31) * 64) * 256;
    int l31 = lane & 31, lh = lane >> 5;
#pragma unroll
    for (int u = 0; u < 8; ++u) {
        int dm = u * 8 + wave * 2 + lh;
        half8 v = *(const half8*)&vlds[dm * 264 + l31 * 8];
        *(half8*)(base + (size_t)dm * 256 + l31 * 8) = v;
    }
}

// ---------------- B: fused cosine attention, QBLK=64, 256 blocks x 1024 thr ----
// Pass 1: 3-buffer 2-deep pipeline, counted vmcnt (never 0 in loop), raw
// s_barrier, 1 barrier/step. LDS: buf0/1/2 @ 0/40960/81920 (K 32KB + Q 8KB
// each); PH overlaps buf0, PV overlaps buf1, pass-2 scratch overlaps buf2.
__global__ __launch_bounds__(1024, 4) void kB(const half_t* __restrict__ Q, const half_t* __restrict__ K,
                                              const half_t* __restrict__ VH, const half_t* __restrict__ VV,
                                              const float* __restrict__ normQ, const float* __restrict__ normK,
                                              const float* __restrict__ temp1, const float* __restrict__ temp2,
                                              half_t* __restrict__ xhv) {
    extern __shared__ char smem[];
    half_t* PH = (half_t*)smem;                  // [64][264] (overlaps buf0)
    half_t* PV = (half_t*)(smem + 40960);        // [64][264] (overlaps buf1)
    float* rq  = (float*)(smem + 122880);        // [64]
    float* rk  = (float*)(smem + 123136);        // [256] -> end 124160

    int idx = blockIdx.x;
    int bh = idx & 63;              // XCD swizzle: same-bh sq-siblings share XCD
    int sqb = idx >> 6;             // 0..3
    int h = bh & 7, b = bh >> 3;
    int sq0 = sqb * 64;
    int tid = threadIdx.x, wave = tid >> 6, lane = tid & 63;
    int l15 = lane & 15, quad = lane >> 4;
    float t1 = temp1[h], t2 = temp2[h];
    const half_t* Qb = Q + (size_t)bh * 256 * 2048;
    const half_t* Kb = K + (size_t)bh * 256 * 2048;
    const half_t* VHb = VH + (size_t)bh * 2048 * 256;
    const half_t* VVb = VV + (size_t)bh * 2048 * 256;

    if (tid < 64) rq[tid] = 1.f / fmaxf(sqrtf(normQ[bh * 256 + sq0 + tid]), 1e-12f);
    if (tid < 256) rk[tid] = 1.f / fmaxf(sqrtf(normK[bh * 256 + tid]), 1e-12f);

    // ---- pass 1: sim = Q.K^T (64 x 256), pipelined. wave w owns t-tile w*16 ----
    {
        const int l7 = lane & 7, l8 = lane >> 3;
        // pre-swizzled global source: LDS slot (row r, s) holds global col16 s^(r&7).
        const int swzh = (l7 ^ (l8 & 7)) * 8;     // halfs offset within 64-half row
        const half_t* gK0 = Kb + (size_t)(wave * 8 + l8) * 2048 + swzh;
        const half_t* gK1 = Kb + (size_t)(128 + wave * 8 + l8) * 2048 + swzh;
        const half_t* gQ  = Qb + (size_t)(sq0 + (wave & 7) * 8 + l8) * 2048 + swzh;

        auto STAGE = [&](int kk, char* B) {
            const int off = kk * 64;              // BK=64 halfs per step
            GLDS(gK0 + off, B + wave * 1024);
            GLDS(gK1 + off, B + 16384 + wave * 1024);
            if (wave < 8) GLDS(gQ + off, B + 32768 + wave * 1024);
        };

        f32x4 acc1[4];
#pragma unroll
        for (int a = 0; a < 4; ++a) acc1[a] = {0.f, 0.f, 0.f, 0.f};
        const int tcol = wave * 16 + l15;
        const int ts7 = tcol & 7;

        auto COMPUTE = [&](const char* B) {
            const half_t* KsB = (const half_t*)B;
            const half_t* QsB = (const half_t*)(B + 32768);
#pragma unroll
            for (int sub = 0; sub < 2; ++sub) {
                int c16 = sub * 4 + quad;         // 16B-slot index = d-slice
                half8 bfr = *(const half8*)(KsB + tcol * 64 + (c16 ^ ts7) * 8);
#pragma unroll
                for (int mt = 0; mt < 4; ++mt) {
                    int m = mt * 16 + l15;
                    half8 afr = *(const half8*)(QsB + m * 64 + (c16 ^ (m & 7)) * 8);
                    acc1[mt] = __builtin_amdgcn_mfma_f32_16x16x32_f16(afr, bfr, acc1[mt], 0, 0, 0);
                }
            }
        };

        STAGE(0, smem);
        STAGE(1, smem + 40960);
        __syncthreads();                          // full drain: buf0/1 + rq/rk ready
        int c0 = 0, c2 = 2;
        for (int kk = 0; kk < 30; ++kk) {
            COMPUTE(smem + c0 * 40960);
            STAGE(kk + 2, smem + c2 * 40960);     // overwrites buf consumed at kk-1
            // counted wait: leave newest stage (kk+2) in flight; stage kk+1 lands.
            if (wave < 8) { asm volatile("s_waitcnt vmcnt(3)" ::: "memory"); }
            else          { asm volatile("s_waitcnt vmcnt(2)" ::: "memory"); }
            __builtin_amdgcn_s_barrier();
            __builtin_amdgcn_sched_barrier(0);
            c0 = (c0 == 2) ? 0 : c0 + 1;
            c2 = (c2 == 2) ? 0 : c2 + 1;
        }
        COMPUTE(smem + c0 * 40960);               // kk=30 (buf0)
        asm volatile("s_waitcnt vmcnt(0)" ::: "memory");
        __builtin_amdgcn_s_barrier();
        __builtin_amdgcn_sched_barrier(0);
        c0 = (c0 == 2) ? 0 : c0 + 1;
        COMPUTE(smem + c0 * 40960);               // kk=31 (buf1)
        // PH dump writes buf0 region; other waves at most read buf1 here - safe.
        float rkt = rk[tcol];
#pragma unroll
        for (int mt = 0; mt < 4; ++mt)
#pragma unroll
            for (int r = 0; r < 4; ++r) {
                int row = mt * 16 + quad * 4 + r;
                PH[row * 264 + tcol] = (half_t)(acc1[mt][r] * rq[row] * rkt);
            }
    }
    __syncthreads();

    // ---- dual softmax: thread owns (row = tid>>4, chunk = tid&15); the 16
    // reducers of a row are contiguous lanes -> pure shuffle reduction ----
    {
        int r_ = tid >> 4, cc = tid & 15;
        half_t* phrow = &PH[r_ * 264 + cc * 16];
        half_t* pvrow = &PV[r_ * 264 + cc * 16];
        half8 v0 = *(const half8*)phrow;
        half8 v1 = *(const half8*)(phrow + 8);
        float fv[16];
#pragma unroll
        for (int e = 0; e < 8; ++e) { fv[e] = (float)v0[e]; fv[8 + e] = (float)v1[e]; }
        float mx = fv[0], mn = fv[0];
#pragma unroll
        for (int e = 1; e < 16; ++e) { mx = fmaxf(mx, fv[e]); mn = fminf(mn, fv[e]); }
#pragma unroll
        for (int m = 1; m < 16; m <<= 1) {
            mx = fmaxf(mx, __shfl_xor(mx, m, 16));
            mn = fminf(mn, __shfl_xor(mn, m, 16));
        }
        float mh = (t1 >= 0.f) ? t1 * mx : t1 * mn;
        float mv = (t2 >= 0.f) ? t2 * mx : t2 * mn;
        float sh = 0.f, sv = 0.f;
#pragma unroll
        for (int e = 0; e < 16; ++e) {
            sh += __expf(fv[e] * t1 - mh);
            sv += __expf(fv[e] * t2 - mv);
        }
#pragma unroll
        for (int m = 1; m < 16; m <<= 1) {
            sh += __shfl_xor(sh, m, 16);
            sv += __shfl_xor(sv, m, 16);
        }
        float rh = 1.f / sh, rv = 1.f / sv;
        half8 o0, o1, p0, p1;
#pragma unroll
        for (int e = 0; e < 8; ++e) {
            o0[e] = (half_t)(__expf(fv[e] * t1 - mh) * rh);
            o1[e] = (half_t)(__expf(fv[8 + e] * t1 - mh) * rh);
            p0[e] = (half_t)(__expf(fv[e] * t2 - mv) * rv);
            p1[e] = (half_t)(__expf(fv[8 + e] * t2 - mv) * rv);
        }
        *(half8*)phrow = o0; *(half8*)(phrow + 8) = o1;
        *(half8*)pvrow = p0; *(half8*)(pvrow + 8) = p1;
    }
    __syncthreads();

    // ---- pass 2: x = P_H@V_H + P_V@V_V. wave w owns d-chunks w*64, w*64+1024.
    // Epilogue: acc2 -> per-wave scratch (dead buf2 region) -> half8 full-line
    // stores to xhv2[b][h][db][s][c]. ----
    const int rr = lane >> 3, c8 = (lane & 7) * 8;
    half_t* myscr = (half_t*)(smem + 81920 + wave * 2560);   // 16x72 halfs + pad
#pragma unroll
    for (int i2 = 0; i2 < 2; ++i2) {
        int d0 = wave * 64 + i2 * 1024;
        f32x4 acc2[4][4];
#pragma unroll
        for (int a = 0; a < 4; ++a)
#pragma unroll
            for (int c = 0; c < 4; ++c) acc2[a][c] = {0.f, 0.f, 0.f, 0.f};
        for (int kc = 0; kc < 8; ++kc) {
            int tk = kc * 32 + quad * 8;
            half8 afr[4];
#pragma unroll
            for (int mt = 0; mt < 4; ++mt)
                afr[mt] = *(const half8*)&PH[(mt * 16 + l15) * 264 + tk];
#pragma unroll
            for (int nt = 0; nt < 4; ++nt) {
                half8 bfr = *(const half8*)(VHb + (size_t)(d0 + nt * 16 + l15) * 256 + tk);
#pragma unroll
                for (int mt = 0; mt < 4; ++mt)
                    acc2[mt][nt] = __builtin_amdgcn_mfma_f32_16x16x32_f16(afr[mt], bfr, acc2[mt][nt], 0, 0, 0);
            }
#pragma unroll
            for (int mt = 0; mt < 4; ++mt)
                afr[mt] = *(const half8*)&PV[(mt * 16 + l15) * 264 + tk];
#pragma unroll
            for (int nt = 0; nt < 4; ++nt) {
                half8 bfr = *(const half8*)(VVb + (size_t)(d0 + nt * 16 + l15) * 256 + tk);
#pragma unroll
                for (int mt = 0; mt < 4; ++mt)
                    acc2[mt][nt] = __builtin_amdgcn_mfma_f32_16x16x32_f16(afr[mt], bfr, acc2[mt][nt], 0, 0, 0);
            }
        }
        int db = wave + i2 * 16;   // d0/64 in [0,32)
        half_t* xbase = xhv + (((size_t)(b * 8 + h) * 32 + db) * 256 + sq0) * 64;
#pragma unroll
        for (int mt = 0; mt < 4; ++mt) {
            // per-wave DS pipe is in-order: reads of slice mt complete before
            // slice mt+1's writes -> single buffer is WAR-safe.
#pragma unroll
            for (int nt = 0; nt < 4; ++nt)
#pragma unroll
                for (int r = 0; r < 4; ++r)
                    myscr[(quad * 4 + r) * 72 + nt * 16 + l15] = (half_t)acc2[mt][nt][r];
#pragma unroll
            for (int u = 0; u < 2; ++u) {
                half8 v = *(const half8*)&myscr[(u * 8 + rr) * 72 + c8];
                *(half8*)(xbase + (size_t)(mt * 16 + u * 8 + rr) * 64 + c8) = v;
            }
        }
    }
}

// ---------------- C: out = xhv2 @ proj_w.T + proj_b ----------------
__global__ __launch_bounds__(256) void kC(const half_t* __restrict__ xhv, const half_t* __restrict__ Wp,
                                          const float* __restrict__ proj_b, float* __restrict__ out) {
    __shared__ float ot[64 * 68];
    int tid = threadIdx.x, wave = tid >> 6, lane = tid & 63;
    int l15 = lane & 15, quad = lane >> 4;
    size_t T0 = (size_t)blockIdx.x * 64;
    int b = (int)(T0 >> 16);
    int s = (int)((T0 >> 8) & 255);
    int n0 = (int)(T0 & 255);
    f32x4 acc[4];
#pragma unroll
    for (int a = 0; a < 4; ++a) acc[a] = {0.f, 0.f, 0.f, 0.f};
#pragma unroll
    for (int kc = 0; kc < 2; ++kc) {
        int c = kc * 32 + quad * 8;
        half8 bfr = *(const half8*)(Wp + (wave * 16 + l15) * 64 + c);
#pragma unroll
        for (int mt = 0; mt < 4; ++mt) {
            int n = n0 + mt * 16 + l15;
            int hh = n >> 5, db = n & 31;
            const half_t* arow = xhv + (((size_t)(b * 8 + hh) * 32 + db) * 256 + s) * 64;
            half8 afr = *(const half8*)(arow + c);
            acc[mt] = __builtin_amdgcn_mfma_f32_16x16x32_f16(afr, bfr, acc[mt], 0, 0, 0);
        }
    }
    float bj = proj_b[wave * 16 + l15];
#pragma unroll
    for (int mt = 0; mt < 4; ++mt)
#pragma unroll
        for (int r = 0; r < 4; ++r)
            ot[(mt * 16 + quad * 4 + r) * 68 + wave * 16 + l15] = acc[mt][r] + bj;
    __syncthreads();
    int row = tid >> 2;
#pragma unroll
    for (int u = 0; u < 4; ++u) {
        int col = (tid & 3) * 4 + u * 16;
        f32x4 v = *(const f32x4*)&ot[row * 68 + col];
        *(f32x4*)(out + (T0 + row) * 64 + col) = v;
    }
}

extern "C" void kernel_launch(void* const* d_in, const int* in_sizes, int n_in,
                              void* d_out, int out_size, void* d_ws, size_t ws_size,
                              hipStream_t stream) {
    const float* x      = (const float*)d_in[0];
    const float* qkv_w  = (const float*)d_in[1];
    const float* qkv_b  = (const float*)d_in[2];
    const float* proj_w = (const float*)d_in[3];
    const float* proj_b = (const float*)d_in[4];
    const float* temp1  = (const float*)d_in[5];
    const float* temp2  = (const float*)d_in[6];
    char* ws = (char*)d_ws;
    half_t* Q   = (half_t*)(ws + WS_Q);
    half_t* K   = (half_t*)(ws + WS_K);
    half_t* VH  = (half_t*)(ws + WS_VH);
    half_t* VV  = (half_t*)(ws + WS_VV);
    half_t* xhv = (half_t*)(ws + WS_XHV);
    float* normQ = (float*)(ws + WS_NQ);
    float* normK = (float*)(ws + WS_NK);
    half_t* Wh  = (half_t*)(ws + WS_WH);
    half_t* Wp  = (half_t*)(ws + WS_WP);
    float* out = (float*)d_out;

    hipFuncSetAttribute((const void*)kB, hipFuncAttributeMaxDynamicSharedMemorySize, 124160);

    kW0<<<1, 256, 0, stream>>>(qkv_w, proj_w, Wh, Wp);
    kA1<<<4096, 256, 0, stream>>>(x, Wh, qkv_b, Q, K, normQ, normK);
    kA2H<<<2048, 256, 0, stream>>>(x, Wh, qkv_b, VH);
    kA2V<<<2048, 256, 0, stream>>>(x, Wh, qkv_b, VV);
    kB<<<256, 1024, 124160, stream>>>(Q, K, VH, VV, normQ, normK, temp1, temp2, xhv);
    kC<<<8192, 256, 0, stream>>>(xhv, Wp, proj_b, out);
}

// Round 7
// 563.570 us; speedup vs baseline: 1.1065x; 1.0403x over previous
//
#include <hip/hip_runtime.h>

// EDTAttention MI355X, round 9: A-side restructure.
// kX: one streaming fp32->fp16 cvt of x (xh aliases XHV region) + weight prep
//     (kills kW0's 1-block whole-device stall).
// kA: kA1+kA2H+kA2V merged into one 8192-block kernel; fragment loads are
//     direct half8 from xh (no cvt/pack, half the read bytes, load->MFMA
//     chain); kA1 norms computed in-register from acc via shuffle reduce.
// kB/kC: unchanged from round-6 verified version (3-buf counted-vmcnt
//     pipeline / full-line xhv2 epilogue).
//
// Index algebra (verified in earlier rounds):
//   Y[b,t,j] = xf @ qkv_w.T + qkv_b,  t = s*256+n, j in [0,256)
//   Q[b,h,s,d]  = Y[b, s*256 +       h*8+ns, j]   d = ns*256+j
//   K[b,h,s,d]  = Y[b, s*256 +  64 + h*8+ns, j]
//   VH[b,h,s,d] = Y[b, s*256 + 128 + h*8+ns, j]
//   VV[b,h,t,d] = Y[b, (h*32+d/64)*256 + 192 + (t/32)*8 + (t%32)/4, (t%4)*64 + d%64]
//   kA2V inverse: element (m=n-192, j) -> dm=j&63, t=32*(m>>3)+4*(m&7)+(j>>6)
//   xhv2[(((b*8+h)*32+db)*256 + s)*64 + c] = attn out for token (b,s,n=h*32+db).

using half_t = _Float16;
using half4 = __attribute__((ext_vector_type(4))) _Float16;
using half8 = __attribute__((ext_vector_type(8))) _Float16;
using f32x4 = __attribute__((ext_vector_type(4))) float;

#define NTOK 524288      // 8*256*256

// async global->LDS, 16B per lane, LDS dest = wave-uniform base + lane*16
#define GLDS(g, l) __builtin_amdgcn_global_load_lds( \
    (const __attribute__((address_space(1))) void*)(g), \
    (__attribute__((address_space(3))) void*)(l), 16, 0, 0)

// ---- workspace layout (bytes) ----
#define WS_Q      0
#define WS_K      67108864
#define WS_VH     134217728
#define WS_VV     201326592
#define WS_XHV    268435456   // dual-use: xh (fp16 x) before kB, xhv after
#define WS_NQ     335544320
#define WS_NK     335609856
#define WS_WH     335675392
#define WS_WP     335708160

// ---------------- X: fp32 x -> fp16 xh (streaming) + weight prep --------------
__global__ __launch_bounds__(256) void kX(const float* __restrict__ x, half_t* __restrict__ xh,
                                          const float* __restrict__ qkv_w, const float* __restrict__ proj_w,
                                          half_t* __restrict__ Wh, half_t* __restrict__ Wp) {
    int tid = threadIdx.x;
    if (blockIdx.x == 0) {
        for (int i = tid; i < 256 * 64; i += 256) Wh[i] = (half_t)qkv_w[i];
        for (int i = tid; i < 64 * 64; i += 256) Wp[i] = (half_t)proj_w[i];
    }
    for (size_t i = (size_t)blockIdx.x * 256 + tid; i < 4194304u; i += 524288u) {
        const float* p = x + i * 8;
        f32x4 f0 = *(const f32x4*)p;
        f32x4 f1 = *(const f32x4*)(p + 4);
        half8 v;
        v[0] = (half_t)f0[0]; v[1] = (half_t)f0[1]; v[2] = (half_t)f0[2]; v[3] = (half_t)f0[3];
        v[4] = (half_t)f1[0]; v[5] = (half_t)f1[1]; v[6] = (half_t)f1[2]; v[7] = (half_t)f1[3];
        *(half8*)(xh + i * 8) = v;
    }
}

// ---------------- A: merged qkv projection (A1 | A2H | A2V by blockIdx) -------
__global__ __launch_bounds__(256) void kA(const half_t* __restrict__ xh,
                                          const half_t* __restrict__ Wh,
                                          const float* __restrict__ qkv_b,
                                          half_t* __restrict__ Q, half_t* __restrict__ K,
                                          half_t* __restrict__ VH, half_t* __restrict__ VV,
                                          float* __restrict__ normQ, float* __restrict__ normK) {
    __shared__ __align__(16) char smem[36992];
    int tid = threadIdx.x, wave = tid >> 6, lane = tid & 63;
    const int l15 = lane & 15, quad = lane >> 4;
    int idx = blockIdx.x;

    if (idx < 4096) {
        // ---- A1: Q and K (g=0,1) + in-register norms ----
        half_t* ylds = (half_t*)smem;            // [64][264]
        float* scr = (float*)(smem + 33792);     // [32]
        int sb = idx & 31; idx >>= 5;
        int h = idx & 7; idx >>= 3;
        int g = idx & 1; int b = idx >> 1;
        int s0 = sb * 8;
        int n0 = g * 64 + h * 8;
        const half_t* xb = xh + (size_t)b * 65536 * 64;
        const int tbase = s0 * 256 + n0;
        f32x4 acc[4][4];   // [i][mt] (swapped orientation: row=j, col=token)
#pragma unroll
        for (int a = 0; a < 4; ++a)
#pragma unroll
            for (int c = 0; c < 4; ++c) acc[a][c] = {0.f, 0.f, 0.f, 0.f};
#pragma unroll
        for (int kc = 0; kc < 2; ++kc) {
            const int c = kc * 32 + quad * 8;
            half8 bx[4];
#pragma unroll
            for (int mt = 0; mt < 4; ++mt) {
                int m = mt * 16 + l15;
                int token = tbase + (m >> 3) * 256 + (m & 7);
                bx[mt] = *(const half8*)(xb + (size_t)token * 64 + c);
            }
#pragma unroll
            for (int i = 0; i < 4; ++i) {
                int j = (wave * 4 + i) * 16 + l15;
                half8 aw = *(const half8*)(Wh + j * 64 + c);
#pragma unroll
                for (int mt = 0; mt < 4; ++mt)
                    acc[i][mt] = __builtin_amdgcn_mfma_f32_16x16x32_f16(aw, bx[mt], acc[i][mt], 0, 0, 0);
            }
        }
        // packed dump + per-token norm partials from fp32 acc
        float nsum[4] = {0.f, 0.f, 0.f, 0.f};
#pragma unroll
        for (int i = 0; i < 4; ++i) {
            int j0 = (wave * 4 + i) * 16 + quad * 4;
            f32x4 bj = *(const f32x4*)&qkv_b[j0];
#pragma unroll
            for (int mt = 0; mt < 4; ++mt) {
                half4 v;
#pragma unroll
                for (int r = 0; r < 4; ++r) {
                    float f = acc[i][mt][r] + bj[r];
                    v[r] = (half_t)f;
                    nsum[mt] += f * f;
                }
                *(half4*)&ylds[(mt * 16 + l15) * 264 + j0] = v;
            }
        }
        // reduce: over ns (l15 bits 0-2) then quad (lane bits 4-5)
#pragma unroll
        for (int mt = 0; mt < 4; ++mt) {
            float v = nsum[mt];
            v += __shfl_xor(v, 1);  v += __shfl_xor(v, 2);  v += __shfl_xor(v, 4);
            v += __shfl_xor(v, 16); v += __shfl_xor(v, 32);
            nsum[mt] = v;
        }
        if (lane == 0 || lane == 8) {
#pragma unroll
            for (int mt = 0; mt < 4; ++mt)
                scr[wave * 8 + mt * 2 + (lane >> 3)] = nsum[mt];
        }
        __syncthreads();
        half_t* dst = (g == 0 ? Q : K) + ((size_t)(b * 8 + h) * 256 + s0) * 2048;
        int ns = tid >> 5, jc = (tid & 31) * 8;
#pragma unroll
        for (int si = 0; si < 8; ++si) {
            half8 v = *(const half8*)&ylds[(si * 8 + ns) * 264 + jc];
            *(half8*)(dst + (size_t)si * 2048 + ns * 256 + jc) = v;
        }
        if (tid < 8) {
            float s = scr[tid] + scr[8 + tid] + scr[16 + tid] + scr[24 + tid];
            float* nd = (g == 0 ? normQ : normK);
            nd[(b * 8 + h) * 256 + s0 + tid] = s;
        }
    } else if (idx < 6144) {
        // ---- A2H: V_H (g=2) -> VH[bh][d][t], packed transposed dump ----
        half_t* yldsT = (half_t*)smem;           // [256][72]
        int id2 = idx - 4096;
        int sb = id2 & 3; id2 >>= 2;
        int nn = id2 & 63; int b = id2 >> 6;
        int h = nn >> 3, ns = nn & 7;
        int n = 128 + nn;
        int s0 = sb * 64;
        const half_t* xb = xh + (size_t)b * 65536 * 64;
        const int tbase = s0 * 256 + n;
        f32x4 acc[4][4];   // [mt][i] (rows = tokens, cols = j)
#pragma unroll
        for (int a = 0; a < 4; ++a)
#pragma unroll
            for (int c = 0; c < 4; ++c) acc[a][c] = {0.f, 0.f, 0.f, 0.f};
#pragma unroll
        for (int kc = 0; kc < 2; ++kc) {
            const int c = kc * 32 + quad * 8;
            half8 afr[4];
#pragma unroll
            for (int mt = 0; mt < 4; ++mt) {
                int m = mt * 16 + l15;
                int token = tbase + (m >> 3) * 2048 + (m & 7) * 256;
                afr[mt] = *(const half8*)(xb + (size_t)token * 64 + c);
            }
#pragma unroll
            for (int i = 0; i < 4; ++i) {
                int j = (wave * 4 + i) * 16 + l15;
                half8 bfr = *(const half8*)(Wh + j * 64 + c);
#pragma unroll
                for (int mt = 0; mt < 4; ++mt)
                    acc[mt][i] = __builtin_amdgcn_mfma_f32_16x16x32_f16(afr[mt], bfr, acc[mt][i], 0, 0, 0);
            }
        }
#pragma unroll
        for (int i = 0; i < 4; ++i) {
            int j = (wave * 4 + i) * 16 + l15;
            float bj = qkv_b[j];
#pragma unroll
            for (int mt = 0; mt < 4; ++mt) {
                half4 v;
#pragma unroll
                for (int r = 0; r < 4; ++r) v[r] = (half_t)(acc[mt][i][r] + bj);
                *(half4*)&yldsT[j * 72 + mt * 16 + quad * 4] = v;
            }
        }
        __syncthreads();
        int jl = lane >> 3, tc = lane & 7;
        half_t* base = VH + ((size_t)(b * 8 + h) * 2048 + ns * 256) * 256 + s0 + tc * 8;
#pragma unroll
        for (int u = 0; u < 8; ++u) {
            int j = wave * 64 + u * 8 + jl;
            half8 v = *(const half8*)&yldsT[j * 72 + tc * 8];
            *(half8*)(base + (size_t)j * 256) = v;
        }
    } else {
        // ---- A2V: V_V (g=3) -> VV[bh][d][t], direct-permuted dump ----
        half_t* vlds = (half_t*)smem;            // [64][264] = [dm][t]
        int id2 = idx - 6144;
        int st = id2 & 255; int b = id2 >> 8;
        int h = st >> 5;
        const half_t* xb = xh + (size_t)b * 65536 * 64;
        const int tbase = st * 256 + 192;
        f32x4 acc[4][4];
#pragma unroll
        for (int a = 0; a < 4; ++a)
#pragma unroll
            for (int c = 0; c < 4; ++c) acc[a][c] = {0.f, 0.f, 0.f, 0.f};
#pragma unroll
        for (int kc = 0; kc < 2; ++kc) {
            const int c = kc * 32 + quad * 8;
            half8 afr[4];
#pragma unroll
            for (int mt = 0; mt < 4; ++mt) {
                int m = mt * 16 + l15;
                int token = tbase + (m >> 3) * 8 + (m & 7);
                afr[mt] = *(const half8*)(xb + (size_t)token * 64 + c);
            }
#pragma unroll
            for (int i = 0; i < 4; ++i) {
                int j = (wave * 4 + i) * 16 + l15;
                half8 bfr = *(const half8*)(Wh + j * 64 + c);
#pragma unroll
                for (int mt = 0; mt < 4; ++mt)
                    acc[mt][i] = __builtin_amdgcn_mfma_f32_16x16x32_f16(afr[mt], bfr, acc[mt][i], 0, 0, 0);
            }
        }
#pragma unroll
        for (int i = 0; i < 4; ++i) {
            int j = (wave * 4 + i) * 16 + l15;
            float bj = qkv_b[j];
            int dm = j & 63;
            int jc = j >> 6;
#pragma unroll
            for (int mt = 0; mt < 4; ++mt)
#pragma unroll
                for (int r = 0; r < 4; ++r) {
                    int m = mt * 16 + quad * 4 + r;
                    int t = 32 * (m >> 3) + 4 * (m & 7) + jc;
                    vlds[dm * 264 + t] = (half_t)(acc[mt][i][r] + bj);
                }
        }
        __syncthreads();
        half_t* base = VV + ((size_t)(b * 8 + h) * 2048 + (st & 31) * 64) * 256;
        int l31 = lane & 31, lh = lane >> 5;
#pragma unroll
        for (int u = 0; u < 8; ++u) {
            int dm = u * 8 + wave * 2 + lh;
            half8 v = *(const half8*)&vlds[dm * 264 + l31 * 8];
            *(half8*)(base + (size_t)dm * 256 + l31 * 8) = v;
        }
    }
}

// ---------------- B: fused cosine attention, QBLK=64, 256 blocks x 1024 thr ----
// Pass 1: 3-buffer 2-deep pipeline, counted vmcnt (never 0 in loop), raw
// s_barrier, 1 barrier/step. LDS: buf0/1/2 @ 0/40960/81920 (K 32KB + Q 8KB
// each); PH overlaps buf0, PV overlaps buf1, pass-2 scratch overlaps buf2.
__global__ __launch_bounds__(1024, 4) void kB(const half_t* __restrict__ Q, const half_t* __restrict__ K,
                                              const half_t* __restrict__ VH, const half_t* __restrict__ VV,
                                              const float* __restrict__ normQ, const float* __restrict__ normK,
                                              const float* __restrict__ temp1, const float* __restrict__ temp2,
                                              half_t* __restrict__ xhv) {
    extern __shared__ char smem[];
    half_t* PH = (half_t*)smem;                  // [64][264] (overlaps buf0)
    half_t* PV = (half_t*)(smem + 40960);        // [64][264] (overlaps buf1)
    float* rq  = (float*)(smem + 122880);        // [64]
    float* rk  = (float*)(smem + 123136);        // [256] -> end 124160

    int idx = blockIdx.x;
    int bh = idx & 63;              // XCD swizzle: same-bh sq-siblings share XCD
    int sqb = idx >> 6;             // 0..3
    int h = bh & 7, b = bh >> 3;
    int sq0 = sqb * 64;
    int tid = threadIdx.x, wave = tid >> 6, lane = tid & 63;
    int l15 = lane & 15, quad = lane >> 4;
    float t1 = temp1[h], t2 = temp2[h];
    const half_t* Qb = Q + (size_t)bh * 256 * 2048;
    const half_t* Kb = K + (size_t)bh * 256 * 2048;
    const half_t* VHb = VH + (size_t)bh * 2048 * 256;
    const half_t* VVb = VV + (size_t)bh * 2048 * 256;

    if (tid < 64) rq[tid] = 1.f / fmaxf(sqrtf(normQ[bh * 256 + sq0 + tid]), 1e-12f);
    if (tid < 256) rk[tid] = 1.f / fmaxf(sqrtf(normK[bh * 256 + tid]), 1e-12f);

    // ---- pass 1: sim = Q.K^T (64 x 256), pipelined. wave w owns t-tile w*16 ----
    {
        const int l7 = lane & 7, l8 = lane >> 3;
        // pre-swizzled global source: LDS slot (row r, s) holds global col16 s^(r&7).
        const int swzh = (l7 ^ (l8 & 7)) * 8;     // halfs offset within 64-half row
        const half_t* gK0 = Kb + (size_t)(wave * 8 + l8) * 2048 + swzh;
        const half_t* gK1 = Kb + (size_t)(128 + wave * 8 + l8) * 2048 + swzh;
        const half_t* gQ  = Qb + (size_t)(sq0 + (wave & 7) * 8 + l8) * 2048 + swzh;

        auto STAGE = [&](int kk, char* B) {
            const int off = kk * 64;              // BK=64 halfs per step
            GLDS(gK0 + off, B + wave * 1024);
            GLDS(gK1 + off, B + 16384 + wave * 1024);
            if (wave < 8) GLDS(gQ + off, B + 32768 + wave * 1024);
        };

        f32x4 acc1[4];
#pragma unroll
        for (int a = 0; a < 4; ++a) acc1[a] = {0.f, 0.f, 0.f, 0.f};
        const int tcol = wave * 16 + l15;
        const int ts7 = tcol & 7;

        auto COMPUTE = [&](const char* B) {
            const half_t* KsB = (const half_t*)B;
            const half_t* QsB = (const half_t*)(B + 32768);
#pragma unroll
            for (int sub = 0; sub < 2; ++sub) {
                int c16 = sub * 4 + quad;         // 16B-slot index = d-slice
                half8 bfr = *(const half8*)(KsB + tcol * 64 + (c16 ^ ts7) * 8);
#pragma unroll
                for (int mt = 0; mt < 4; ++mt) {
                    int m = mt * 16 + l15;
                    half8 afr = *(const half8*)(QsB + m * 64 + (c16 ^ (m & 7)) * 8);
                    acc1[mt] = __builtin_amdgcn_mfma_f32_16x16x32_f16(afr, bfr, acc1[mt], 0, 0, 0);
                }
            }
        };

        STAGE(0, smem);
        STAGE(1, smem + 40960);
        __syncthreads();                          // full drain: buf0/1 + rq/rk ready
        int c0 = 0, c2 = 2;
        for (int kk = 0; kk < 30; ++kk) {
            COMPUTE(smem + c0 * 40960);
            STAGE(kk + 2, smem + c2 * 40960);     // overwrites buf consumed at kk-1
            // counted wait: leave newest stage (kk+2) in flight; stage kk+1 lands.
            if (wave < 8) { asm volatile("s_waitcnt vmcnt(3)" ::: "memory"); }
            else          { asm volatile("s_waitcnt vmcnt(2)" ::: "memory"); }
            __builtin_amdgcn_s_barrier();
            __builtin_amdgcn_sched_barrier(0);
            c0 = (c0 == 2) ? 0 : c0 + 1;
            c2 = (c2 == 2) ? 0 : c2 + 1;
        }
        COMPUTE(smem + c0 * 40960);               // kk=30 (buf0)
        asm volatile("s_waitcnt vmcnt(0)" ::: "memory");
        __builtin_amdgcn_s_barrier();
        __builtin_amdgcn_sched_barrier(0);
        c0 = (c0 == 2) ? 0 : c0 + 1;
        COMPUTE(smem + c0 * 40960);               // kk=31 (buf1)
        // PH dump writes buf0 region; other waves at most read buf1 here - safe.
        float rkt = rk[tcol];
#pragma unroll
        for (int mt = 0; mt < 4; ++mt)
#pragma unroll
            for (int r = 0; r < 4; ++r) {
                int row = mt * 16 + quad * 4 + r;
                PH[row * 264 + tcol] = (half_t)(acc1[mt][r] * rq[row] * rkt);
            }
    }
    __syncthreads();

    // ---- dual softmax: thread owns (row = tid>>4, chunk = tid&15); the 16
    // reducers of a row are contiguous lanes -> pure shuffle reduction ----
    {
        int r_ = tid >> 4, cc = tid & 15;
        half_t* phrow = &PH[r_ * 264 + cc * 16];
        half_t* pvrow = &PV[r_ * 264 + cc * 16];
        half8 v0 = *(const half8*)phrow;
        half8 v1 = *(const half8*)(phrow + 8);
        float fv[16];
#pragma unroll
        for (int e = 0; e < 8; ++e) { fv[e] = (float)v0[e]; fv[8 + e] = (float)v1[e]; }
        float mx = fv[0], mn = fv[0];
#pragma unroll
        for (int e = 1; e < 16; ++e) { mx = fmaxf(mx, fv[e]); mn = fminf(mn, fv[e]); }
#pragma unroll
        for (int m = 1; m < 16; m <<= 1) {
            mx = fmaxf(mx, __shfl_xor(mx, m, 16));
            mn = fminf(mn, __shfl_xor(mn, m, 16));
        }
        float mh = (t1 >= 0.f) ? t1 * mx : t1 * mn;
        float mv = (t2 >= 0.f) ? t2 * mx : t2 * mn;
        float sh = 0.f, sv = 0.f;
#pragma unroll
        for (int e = 0; e < 16; ++e) {
            sh += __expf(fv[e] * t1 - mh);
            sv += __expf(fv[e] * t2 - mv);
        }
#pragma unroll
        for (int m = 1; m < 16; m <<= 1) {
            sh += __shfl_xor(sh, m, 16);
            sv += __shfl_xor(sv, m, 16);
        }
        float rh = 1.f / sh, rv = 1.f / sv;
        half8 o0, o1, p0, p1;
#pragma unroll
        for (int e = 0; e < 8; ++e) {
            o0[e] = (half_t)(__expf(fv[e] * t1 - mh) * rh);
            o1[e] = (half_t)(__expf(fv[8 + e] * t1 - mh) * rh);
            p0[e] = (half_t)(__expf(fv[e] * t2 - mv) * rv);
            p1[e] = (half_t)(__expf(fv[8 + e] * t2 - mv) * rv);
        }
        *(half8*)phrow = o0; *(half8*)(phrow + 8) = o1;
        *(half8*)pvrow = p0; *(half8*)(pvrow + 8) = p1;
    }
    __syncthreads();

    // ---- pass 2: x = P_H@V_H + P_V@V_V. wave w owns d-chunks w*64, w*64+1024.
    // Epilogue: acc2 -> per-wave scratch (dead buf2 region) -> half8 full-line
    // stores to xhv2[b][h][db][s][c]. ----
    const int rr = lane >> 3, c8 = (lane & 7) * 8;
    half_t* myscr = (half_t*)(smem + 81920 + wave * 2560);   // 16x72 halfs + pad
#pragma unroll
    for (int i2 = 0; i2 < 2; ++i2) {
        int d0 = wave * 64 + i2 * 1024;
        f32x4 acc2[4][4];
#pragma unroll
        for (int a = 0; a < 4; ++a)
#pragma unroll
            for (int c = 0; c < 4; ++c) acc2[a][c] = {0.f, 0.f, 0.f, 0.f};
        for (int kc = 0; kc < 8; ++kc) {
            int tk = kc * 32 + quad * 8;
            half8 afr[4];
#pragma unroll
            for (int mt = 0; mt < 4; ++mt)
                afr[mt] = *(const half8*)&PH[(mt * 16 + l15) * 264 + tk];
#pragma unroll
            for (int nt = 0; nt < 4; ++nt) {
                half8 bfr = *(const half8*)(VHb + (size_t)(d0 + nt * 16 + l15) * 256 + tk);
#pragma unroll
                for (int mt = 0; mt < 4; ++mt)
                    acc2[mt][nt] = __builtin_amdgcn_mfma_f32_16x16x32_f16(afr[mt], bfr, acc2[mt][nt], 0, 0, 0);
            }
#pragma unroll
            for (int mt = 0; mt < 4; ++mt)
                afr[mt] = *(const half8*)&PV[(mt * 16 + l15) * 264 + tk];
#pragma unroll
            for (int nt = 0; nt < 4; ++nt) {
                half8 bfr = *(const half8*)(VVb + (size_t)(d0 + nt * 16 + l15) * 256 + tk);
#pragma unroll
                for (int mt = 0; mt < 4; ++mt)
                    acc2[mt][nt] = __builtin_amdgcn_mfma_f32_16x16x32_f16(afr[mt], bfr, acc2[mt][nt], 0, 0, 0);
            }
        }
        int db = wave + i2 * 16;   // d0/64 in [0,32)
        half_t* xbase = xhv + (((size_t)(b * 8 + h) * 32 + db) * 256 + sq0) * 64;
#pragma unroll
        for (int mt = 0; mt < 4; ++mt) {
            // per-wave DS pipe is in-order: reads of slice mt complete before
            // slice mt+1's writes -> single buffer is WAR-safe.
#pragma unroll
            for (int nt = 0; nt < 4; ++nt)
#pragma unroll
                for (int r = 0; r < 4; ++r)
                    myscr[(quad * 4 + r) * 72 + nt * 16 + l15] = (half_t)acc2[mt][nt][r];
#pragma unroll
            for (int u = 0; u < 2; ++u) {
                half8 v = *(const half8*)&myscr[(u * 8 + rr) * 72 + c8];
                *(half8*)(xbase + (size_t)(mt * 16 + u * 8 + rr) * 64 + c8) = v;
            }
        }
    }
}

// ---------------- C: out = xhv2 @ proj_w.T + proj_b ----------------
__global__ __launch_bounds__(256) void kC(const half_t* __restrict__ xhv, const half_t* __restrict__ Wp,
                                          const float* __restrict__ proj_b, float* __restrict__ out) {
    __shared__ float ot[64 * 68];
    int tid = threadIdx.x, wave = tid >> 6, lane = tid & 63;
    int l15 = lane & 15, quad = lane >> 4;
    size_t T0 = (size_t)blockIdx.x * 64;
    int b = (int)(T0 >> 16);
    int s = (int)((T0 >> 8) & 255);
    int n0 = (int)(T0 & 255);
    f32x4 acc[4];
#pragma unroll
    for (int a = 0; a < 4; ++a) acc[a] = {0.f, 0.f, 0.f, 0.f};
#pragma unroll
    for (int kc = 0; kc < 2; ++kc) {
        int c = kc * 32 + quad * 8;
        half8 bfr = *(const half8*)(Wp + (wave * 16 + l15) * 64 + c);
#pragma unroll
        for (int mt = 0; mt < 4; ++mt) {
            int n = n0 + mt * 16 + l15;
            int hh = n >> 5, db = n & 31;
            const half_t* arow = xhv + (((size_t)(b * 8 + hh) * 32 + db) * 256 + s) * 64;
            half8 afr = *(const half8*)(arow + c);
            acc[mt] = __builtin_amdgcn_mfma_f32_16x16x32_f16(afr, bfr, acc[mt], 0, 0, 0);
        }
    }
    float bj = proj_b[wave * 16 + l15];
#pragma unroll
    for (int mt = 0; mt < 4; ++mt)
#pragma unroll
        for (int r = 0; r < 4; ++r)
            ot[(mt * 16 + quad * 4 + r) * 68 + wave * 16 + l15] = acc[mt][r] + bj;
    __syncthreads();
    int row = tid >> 2;
#pragma unroll
    for (int u = 0; u < 4; ++u) {
        int col = (tid & 3) * 4 + u * 16;
        f32x4 v = *(const f32x4*)&ot[row * 68 + col];
        *(f32x4*)(out + (T0 + row) * 64 + col) = v;
    }
}

extern "C" void kernel_launch(void* const* d_in, const int* in_sizes, int n_in,
                              void* d_out, int out_size, void* d_ws, size_t ws_size,
                              hipStream_t stream) {
    const float* x      = (const float*)d_in[0];
    const float* qkv_w  = (const float*)d_in[1];
    const float* qkv_b  = (const float*)d_in[2];
    const float* proj_w = (const float*)d_in[3];
    const float* proj_b = (const float*)d_in[4];
    const float* temp1  = (const float*)d_in[5];
    const float* temp2  = (const float*)d_in[6];
    char* ws = (char*)d_ws;
    half_t* Q   = (half_t*)(ws + WS_Q);
    half_t* K   = (half_t*)(ws + WS_K);
    half_t* VH  = (half_t*)(ws + WS_VH);
    half_t* VV  = (half_t*)(ws + WS_VV);
    half_t* xh  = (half_t*)(ws + WS_XHV);   // fp16 x, consumed by kA...
    half_t* xhv = (half_t*)(ws + WS_XHV);   // ...then overwritten by kB
    float* normQ = (float*)(ws + WS_NQ);
    float* normK = (float*)(ws + WS_NK);
    half_t* Wh  = (half_t*)(ws + WS_WH);
    half_t* Wp  = (half_t*)(ws + WS_WP);
    float* out = (float*)d_out;

    hipFuncSetAttribute((const void*)kB, hipFuncAttributeMaxDynamicSharedMemorySize, 124160);

    kX<<<2048, 256, 0, stream>>>(x, xh, qkv_w, proj_w, Wh, Wp);
    kA<<<8192, 256, 0, stream>>>(xh, Wh, qkv_b, Q, K, VH, VV, normQ, normK);
    kB<<<256, 1024, 124160, stream>>>(Q, K, VH, VV, normQ, normK, temp1, temp2, xhv);
    kC<<<8192, 256, 0, stream>>>(xhv, Wp, proj_b, out);
}